// Round 1
// baseline (15205.057 us; speedup 1.0000x reference)
//
#include <hip/hip_runtime.h>
#include <math.h>

#define EPSV 1e-5f

__device__ __forceinline__ float sigf(float x){ return 1.0f/(1.0f+expf(-x)); }

// ---------------- LN over channel dim (ln_clamp, axes=(1,)) -> channel-last seq ----------------
// mode 0 (intra): dst[((b*250+t)*65 + q)*48 + c]
// mode 1 (inter): dst[((b*65+q)*250 + t)*48 + c]
__global__ void k_ln_chan(const float* __restrict__ src, float* __restrict__ dst,
                          const float* __restrict__ g, const float* __restrict__ bb, int mode){
  int i = blockIdx.x*blockDim.x + threadIdx.x;
  const int total = 2*250*65;
  if (i >= total) return;
  int q = i % 65; int t = (i/65) % 250; int b = i/(65*250);
  const float* p = src + (size_t)b*48*250*65 + (size_t)t*65 + q;
  float s=0.f, ss=0.f;
  for (int c=0;c<48;c++){ float v = p[(size_t)c*250*65]; s+=v; ss+=v*v; }
  float mu = s*(1.0f/48.0f);
  float var = ss*(1.0f/48.0f) - mu*mu;
  float rs = rsqrtf(fmaxf(var, EPSV));
  float* d = (mode==0) ? dst + ((size_t)(b*250+t)*65 + q)*48
                       : dst + ((size_t)(b*65+q)*250 + t)*48;
  for (int c=0;c<48;c++){ float v = p[(size_t)c*250*65]; d[c] = (v-mu)*rs*g[c] + bb[c]; }
}

// ---------------- qkv = seq @ in_w.T + in_b ----------------
__global__ void k_qkv(const float* __restrict__ seq, const float* __restrict__ w,
                      const float* __restrict__ bias, float* __restrict__ qkv, int NL){
  int i = blockIdx.x*blockDim.x + threadIdx.x;
  if (i >= NL*144) return;
  int j = i % 144; int nl = i / 144;
  const float* srow = seq + (size_t)nl*48;
  const float* wrow = w + j*48;
  float acc = bias[j];
  for (int c=0;c<48;c++) acc += srow[c]*wrow[c];
  qkv[i] = acc;
}

// ---------------- MHA core (per (n,h) block), dh=12, online softmax ----------------
__global__ void k_mha(const float* __restrict__ qkv, float* __restrict__ att, int N, int L){
  __shared__ float shq[250*12];
  __shared__ float shk[250*12];
  __shared__ float shv[250*12];
  int n = blockIdx.x, h = blockIdx.y;
  const float* base = qkv + (size_t)n*L*144 + h*12;
  for (int i = threadIdx.x; i < L*12; i += blockDim.x){
    int l = i/12, d = i%12;
    shq[i] = base[(size_t)l*144 + d];
    shk[i] = base[(size_t)l*144 + 48 + d];
    shv[i] = base[(size_t)l*144 + 96 + d];
  }
  __syncthreads();
  const float scale = 0.28867513459481287f; // 1/sqrt(12)
  for (int r = threadIdx.x; r < L; r += blockDim.x){
    float m = -1e30f, den = 0.0f, o[12];
    for (int d=0; d<12; d++) o[d]=0.0f;
    const float* qr = shq + r*12;
    for (int j=0; j<L; j++){
      const float* kr = shk + j*12;
      float s = 0.f;
      for (int d=0; d<12; d++) s += qr[d]*kr[d];
      s *= scale;
      if (s > m){
        float corr = expf(m - s);
        den *= corr;
        for (int d=0; d<12; d++) o[d] *= corr;
        m = s;
      }
      float e = expf(s - m);
      den += e;
      const float* vr = shv + j*12;
      for (int d=0; d<12; d++) o[d] += e*vr[d];
    }
    float inv = 1.0f/den;
    float* outp = att + ((size_t)n*L + r)*48 + h*12;
    for (int d=0; d<12; d++) outp[d] = o[d]*inv;
  }
}

// ---------------- out proj + residual ----------------
__global__ void k_projres(const float* __restrict__ att, const float* __restrict__ seq,
                          const float* __restrict__ w, const float* __restrict__ bias,
                          float* __restrict__ dst, int NL){
  int i = blockIdx.x*blockDim.x + threadIdx.x;
  if (i >= NL*48) return;
  int o = i % 48; int nl = i/48;
  const float* ar = att + (size_t)nl*48;
  const float* wr = w + o*48;
  float acc = bias[o] + seq[i];
  for (int c=0;c<48;c++) acc += ar[c]*wr[c];
  dst[i] = acc;
}

// ---------------- torch_ln over last dim (48), in place ----------------
__global__ void k_rowln(float* __restrict__ buf, const float* __restrict__ g,
                        const float* __restrict__ bb, int NL){
  int nl = blockIdx.x*blockDim.x + threadIdx.x;
  if (nl >= NL) return;
  float* p = buf + (size_t)nl*48;
  float s=0.f, ss=0.f;
  for (int c=0;c<48;c++){ float v=p[c]; s+=v; ss+=v*v; }
  float mu = s*(1.0f/48.0f);
  float var = ss*(1.0f/48.0f) - mu*mu;
  float rs = rsqrtf(var + EPSV);
  for (int c=0;c<48;c++) p[c] = (p[c]-mu)*rs*g[c] + bb[c];
}

// ---------------- transpose 768x192 -> wT[d*768+row] ----------------
__global__ void k_wt(const float* __restrict__ w, float* __restrict__ wt){
  int i = blockIdx.x*blockDim.x + threadIdx.x;
  if (i >= 768*192) return;
  int row = i / 192, d = i % 192;
  wt[d*768 + row] = w[i];
}

// ---------------- biLSTM scan: G=4 sequences per block, 192 threads (one per hidden) ----------
// gridDim = (ceil(N/4), 2 dirs). u_l is computed on the fly from channel-last seq2 (unfold).
__global__ __launch_bounds__(192) void k_lstm(
    const float* __restrict__ seq2, float* __restrict__ r,
    const float* __restrict__ wiT_f, const float* __restrict__ whT_f,
    const float* __restrict__ bi_f, const float* __restrict__ bh_f,
    const float* __restrict__ wiT_b, const float* __restrict__ whT_b,
    const float* __restrict__ bi_b, const float* __restrict__ bh_b,
    int N, int L2, int SL){
  __shared__ float ush[4][192];
  __shared__ float hsh[4][192];
  int dir = blockIdx.y;
  int n0 = blockIdx.x*4;
  int j = threadIdx.x;
  const float* wiT = dir ? wiT_b : wiT_f;
  const float* whT = dir ? whT_b : whT_f;
  const float* bi  = dir ? bi_b  : bi_f;
  const float* bh  = dir ? bh_b  : bh_f;
  float bsum[4];
  for (int gix=0; gix<4; gix++) bsum[gix] = bi[gix*192+j] + bh[gix*192+j];
  float cst[4] = {0.f,0.f,0.f,0.f};
  for (int s=0;s<4;s++) hsh[s][j] = 0.0f;
  int cch = j>>2, kk = j&3;   // u index j == c*4+k
  __syncthreads();
  for (int step=0; step<L2; step++){
    int l = dir ? (L2-1-step) : step;
    for (int s=0;s<4;s++){
      ush[s][j] = (n0+s < N) ? seq2[((size_t)(n0+s)*SL + l + kk)*48 + cch] : 0.0f;
    }
    __syncthreads();
    float a0[4], a1[4], a2[4], a3[4];
    for (int s=0;s<4;s++){ a0[s]=bsum[0]; a1[s]=bsum[1]; a2[s]=bsum[2]; a3[s]=bsum[3]; }
    for (int d=0; d<192; d++){
      const float* wic = wiT + d*768;
      const float* whc = whT + d*768;
      float wi0 = wic[j],     wi1 = wic[192+j], wi2 = wic[384+j], wi3 = wic[576+j];
      float wh0 = whc[j],     wh1 = whc[192+j], wh2 = whc[384+j], wh3 = whc[576+j];
      for (int s=0;s<4;s++){
        float u = ush[s][d], hh = hsh[s][d];
        a0[s] += u*wi0 + hh*wh0;
        a1[s] += u*wi1 + hh*wh1;
        a2[s] += u*wi2 + hh*wh2;
        a3[s] += u*wi3 + hh*wh3;
      }
    }
    __syncthreads();
    for (int s=0;s<4;s++){
      if (n0+s < N){
        float ig = sigf(a0[s]), fg = sigf(a1[s]);
        float gg = tanhf(a2[s]), og = sigf(a3[s]);
        cst[s] = fg*cst[s] + ig*gg;
        float hn = og*tanhf(cst[s]);
        hsh[s][j] = hn;
        r[((size_t)(n0+s)*L2 + l)*384 + dir*192 + j] = hn;
      }
    }
    __syncthreads();
  }
}

// ---------------- conv_transpose1d(stride=1,KS=4) + bias + residual ----------------
// mode 0: intra, n=b*250+t, pos=q ; mode 1: inter, n=b*65+q, pos=t. out idx ((b*48+c)*250+t)*65+q.
__global__ void k_convt(const float* __restrict__ r, const float* __restrict__ w,
                        const float* __restrict__ bias, const float* __restrict__ resid,
                        float* __restrict__ dst, int N, int L2, int OL, int mode){
  int i = blockIdx.x*blockDim.x + threadIdx.x;
  if (i >= N*48*OL) return;
  int pos = i % OL; int c = (i/OL) % 48; int n = i/(OL*48);
  float acc = bias[c];
  for (int k=0;k<4;k++){
    int l = pos - k;
    if (l >= 0 && l < L2){
      const float* rr = r + ((size_t)n*L2 + l)*384;
      const float* wr = w + c*4 + k;
      for (int ii=0; ii<384; ii++) acc += rr[ii]*wr[(size_t)ii*192];
    }
  }
  size_t oidx;
  if (mode==0){ int b = n/250, t = n%250; oidx = (((size_t)b*48+c)*250+t)*65 + pos; }
  else        { int b = n/65,  q = n%65;  oidx = (((size_t)b*48+c)*250+pos)*65 + q; }
  dst[oidx] = acc + resid[oidx];
}

// ---------------- head projection + per-head leaky ----------------
// dst layout (((h*2+b)*250+t)*dim+e)*65+f  == thread index i
__global__ void k_headproj(const float* __restrict__ bt, const float* __restrict__ w,
                           const float* __restrict__ bias, const float* __restrict__ alpha,
                           float* __restrict__ dst, int dim){
  int i = blockIdx.x*blockDim.x + threadIdx.x;
  int total = 4*2*250*dim*65;
  if (i >= total) return;
  int f = i % 65;
  int e = (i/65) % dim;
  int t = (i/(65*dim)) % 250;
  int b = (i/(65*dim*250)) % 2;
  int h = i/(65*dim*250*2);
  const float* wr = w + (h*dim+e)*48;
  const float* bp = bt + (size_t)b*48*250*65 + (size_t)t*65 + f;
  float acc = bias[h*dim+e];
  for (int c=0;c<48;c++) acc += bp[(size_t)c*250*65]*wr[c];
  if (acc < 0.f) acc *= alpha[h];
  dst[i] = acc;
}

// ---------------- ln_clamp over (e,f) per (h,b,t) block, in place ----------------
__global__ void k_headln(float* __restrict__ buf, const float* __restrict__ g,
                         const float* __restrict__ bt_, int dim){
  __shared__ float r1[256];
  __shared__ float r2[256];
  int bx = blockIdx.x;        // (h*2+b)*250+t
  int h = bx/500;
  int n = dim*65;
  float* p = buf + (size_t)bx*n;
  const float* gp = g + h*n;
  const float* bp = bt_ + h*n;
  float s=0.f, ss=0.f;
  for (int k=threadIdx.x; k<n; k+=256){ float v=p[k]; s+=v; ss+=v*v; }
  r1[threadIdx.x]=s; r2[threadIdx.x]=ss; __syncthreads();
  for (int st=128; st>0; st>>=1){
    if (threadIdx.x < st){ r1[threadIdx.x]+=r1[threadIdx.x+st]; r2[threadIdx.x]+=r2[threadIdx.x+st]; }
    __syncthreads();
  }
  float mu = r1[0]/(float)n, var = r2[0]/(float)n - mu*mu;
  float rs = rsqrtf(fmaxf(var, EPSV));
  for (int k=threadIdx.x; k<n; k+=256) p[k] = (p[k]-mu)*rs*gp[k] + bp[k];
}

// ---------------- flattened-head attention: block per (h,b,t) ----------------
__global__ void k_headattn(const float* __restrict__ Qp, const float* __restrict__ Kp,
                           const float* __restrict__ Vp, float* __restrict__ Vo){
  __shared__ float qsh[520];
  __shared__ float psh[250];
  __shared__ float r1[256];
  int bx = blockIdx.x;
  int t = bx % 250;
  int b = (bx/250) % 2;
  int h = bx/500;
  int hb = h*2 + b;
  const float* qrow = Qp + ((size_t)hb*250 + t)*520;
  for (int d=threadIdx.x; d<520; d+=256) qsh[d] = qrow[d];
  __syncthreads();
  const float scale = rsqrtf(520.0f);
  float lmax = -1e30f;
  for (int s2=threadIdx.x; s2<250; s2+=256){
    const float* kr = Kp + ((size_t)hb*250 + s2)*520;
    float acc = 0.f;
    for (int d=0; d<520; d++) acc += qsh[d]*kr[d];
    acc *= scale;
    psh[s2] = acc;
    lmax = fmaxf(lmax, acc);
  }
  r1[threadIdx.x] = lmax; __syncthreads();
  for (int st=128; st>0; st>>=1){
    if (threadIdx.x<st) r1[threadIdx.x]=fmaxf(r1[threadIdx.x], r1[threadIdx.x+st]);
    __syncthreads();
  }
  float m = r1[0];
  __syncthreads();
  float lsum = 0.f;
  for (int s2=threadIdx.x; s2<250; s2+=256){
    float e = expf(psh[s2]-m);
    psh[s2] = e;
    lsum += e;
  }
  r1[threadIdx.x]=lsum; __syncthreads();
  for (int st=128; st>0; st>>=1){
    if (threadIdx.x<st) r1[threadIdx.x]+=r1[threadIdx.x+st];
    __syncthreads();
  }
  float inv = 1.0f/r1[0];
  for (int d=threadIdx.x; d<780; d+=256){
    float acc = 0.f;
    const float* vcol = Vp + (size_t)hb*250*780 + d;
    for (int s2=0; s2<250; s2++) acc += psh[s2]*vcol[(size_t)s2*780];
    acc *= inv;
    int e = d/65, f = d%65;
    Vo[(((size_t)b*48 + h*12 + e)*250 + t)*65 + f] = acc;
  }
}

// ---------------- p-projection + leaky (scalar alpha) ----------------
__global__ void k_pproj(const float* __restrict__ Vo, const float* __restrict__ pw,
                        const float* __restrict__ pb, const float* __restrict__ pa,
                        float* __restrict__ pj){
  int i = blockIdx.x*blockDim.x + threadIdx.x;
  if (i >= 2*48*250*65) return;
  int f = i % 65;
  int t = (i/65) % 250;
  int o = (i/(65*250)) % 48;
  int b = i/(65*250*48);
  const float* vp = Vo + (size_t)b*48*250*65 + (size_t)t*65 + f;
  const float* wr = pw + o*48;
  float acc = pb[o];
  for (int c=0;c<48;c++) acc += vp[(size_t)c*250*65]*wr[c];
  if (acc < 0.f) acc *= pa[0];
  pj[i] = acc;
}

// ---------------- ln_clamp over (c,f) per (b,t) + residual(inter) ----------------
__global__ void k_pln(const float* __restrict__ pj, const float* __restrict__ pg,
                      const float* __restrict__ pbt, const float* __restrict__ inter,
                      float* __restrict__ outb){
  __shared__ float r1[256];
  __shared__ float r2[256];
  int bx = blockIdx.x; // b*250+t
  int t = bx % 250, b = bx/250;
  const float* base = pj + (size_t)b*48*250*65 + (size_t)t*65;
  float s=0.f, ss=0.f;
  for (int k=threadIdx.x; k<3120; k+=256){
    int c = k/65, f = k%65;
    float v = base[(size_t)c*250*65 + f];
    s+=v; ss+=v*v;
  }
  r1[threadIdx.x]=s; r2[threadIdx.x]=ss; __syncthreads();
  for (int st=128; st>0; st>>=1){
    if (threadIdx.x<st){ r1[threadIdx.x]+=r1[threadIdx.x+st]; r2[threadIdx.x]+=r2[threadIdx.x+st]; }
    __syncthreads();
  }
  float mu = r1[0]*(1.0f/3120.0f), var = r2[0]*(1.0f/3120.0f) - mu*mu;
  float rs = rsqrtf(fmaxf(var, EPSV));
  for (int k=threadIdx.x; k<3120; k+=256){
    int c = k/65, f = k%65;
    size_t idx = (((size_t)b*48+c)*250 + t)*65 + f;
    float v = pj[idx];
    outb[idx] = (v-mu)*rs*pg[c*65+f] + pbt[c*65+f] + inter[idx];
  }
}

// ---------------- fin 1x1: (B,48,...) -> (B,384,...) ----------------
__global__ void k_fin(const float* __restrict__ outb, const float* __restrict__ w,
                      const float* __restrict__ bias, float* __restrict__ pi){
  int i = blockIdx.x*blockDim.x + threadIdx.x;
  if (i >= 2*384*250*65) return;
  int f = i % 65;
  int t = (i/65) % 250;
  int o = (i/(65*250)) % 384;
  int b = i/(65*250*384);
  const float* xp = outb + (size_t)b*48*250*65 + (size_t)t*65 + f;
  const float* wr = w + o*48;
  float acc = bias[o];
  for (int c=0;c<48;c++) acc += xp[(size_t)c*250*65]*wr[c];
  pi[i] = acc;
}

// ---------------- fused depthwise 3x3 (pad 1) on both halves + gelu-gate ----------------
__global__ void k_dwg(const float* __restrict__ pi, const float* __restrict__ dw,
                      const float* __restrict__ db, float* __restrict__ gbuf){
  int i = blockIdx.x*blockDim.x + threadIdx.x;
  if (i >= 2*192*250*65) return;
  int f = i % 65;
  int t = (i/65) % 250;
  int j = (i/(65*250)) % 192;
  int b = i/(65*250*192);
  float x12[2];
  for (int half=0; half<2; half++){
    int ch = j + half*192;
    const float* base = pi + ((size_t)b*384 + ch)*250*65;
    const float* wr = dw + ch*9;
    float acc = db[ch];
    for (int dt=-1; dt<=1; dt++){
      int tt = t+dt;
      if (tt<0||tt>=250) continue;
      for (int df=-1; df<=1; df++){
        int ff = f+df;
        if (ff<0||ff>=65) continue;
        acc += base[(size_t)tt*65+ff]*wr[(dt+1)*3 + (df+1)];
      }
    }
    x12[half]=acc;
  }
  float x1 = x12[0];
  float g = 0.5f*x1*(1.0f+erff(x1*0.70710678118654752f));
  gbuf[i] = g * x12[1];
}

// ---------------- final 1x1 (192->48) + residual -> d_out ----------------
__global__ void k_final(const float* __restrict__ gbuf, const float* __restrict__ w,
                        const float* __restrict__ bias, const float* __restrict__ outb,
                        float* __restrict__ dout){
  int i = blockIdx.x*blockDim.x + threadIdx.x;
  if (i >= 2*48*250*65) return;
  int f = i % 65;
  int t = (i/65) % 250;
  int o = (i/(65*250)) % 48;
  int b = i/(65*250*48);
  const float* gp = gbuf + (size_t)b*192*250*65 + (size_t)t*65 + f;
  const float* wr = w + o*192;
  float acc = bias[o];
  for (int j=0;j<192;j++) acc += gp[(size_t)j*250*65]*wr[j];
  dout[i] = acc + outb[i];
}

extern "C" void kernel_launch(void* const* d_in, const int* in_sizes, int n_in,
                              void* d_out, int out_size, void* d_ws, size_t ws_size,
                              hipStream_t stream) {
  (void)in_sizes; (void)n_in; (void)out_size; (void)ws_size;
  auto in = [&](int i){ return (const float*)d_in[i]; };
  const float* x        = in(0);
  const float* af_in_w  = in(1);  const float* af_in_b  = in(2);
  const float* af_out_w = in(3);  const float* af_out_b = in(4);
  const float* at_in_w  = in(5);  const float* at_in_b  = in(6);
  const float* at_out_w = in(7);  const float* at_out_b = in(8);
  const float* naf_g = in(9),  *naf_b = in(10), *nat_g = in(11), *nat_b = in(12);
  const float* intra_ng = in(13), *intra_nb = in(14), *inter_ng = in(15), *inter_nb = in(16);
  const float* intra_wif = in(17), *intra_whf = in(18), *intra_bif = in(19), *intra_bhf = in(20);
  const float* intra_wib = in(21), *intra_whb = in(22), *intra_bib = in(23), *intra_bhb = in(24);
  const float* inter_wif = in(25), *inter_whf = in(26), *inter_bif = in(27), *inter_bhf = in(28);
  const float* inter_wib = in(29), *inter_whb = in(30), *inter_bib = in(31), *inter_bhb = in(32);
  const float* il_w = in(33), *il_b = in(34), *itl_w = in(35), *itl_b = in(36);
  const float* qw = in(37), *qb = in(38), *qa = in(39), *qg = in(40), *qbt = in(41);
  const float* kw = in(42), *kb = in(43), *ka = in(44), *kg = in(45), *kbt = in(46);
  const float* vw = in(47), *vb = in(48), *va = in(49), *vg = in(50), *vbt = in(51);
  const float* pw = in(52), *pb = in(53), *pa = in(54), *pg = in(55), *pbt = in(56);
  const float* fin_w = in(57), *fin_b = in(58), *fdw_w = in(59), *fdw_b = in(60);
  const float* fout_w = in(61), *fout_b = in(62);

  float* ws = (float*)d_ws;
  float* buf_intra = ws + 0;            // 1,560,000
  float* buf_bt    = ws + 1560000;      // 1,560,000
  float* buf_out   = ws + 3120000;      // 1,560,000
  float* wT        = ws + 4680000;      // 8 * 147,456
  float* scr       = ws + 5859648;      // scratch arena (~21.7M floats)
  float* s_seq  = scr;                  // 1,560,000
  float* s_qkv  = scr + 1560000;        // 4,680,000
  float* s_att  = scr + 6240000;        // 1,560,000
  float* s_seq2 = scr + 7800000;        // 1,560,000
  float* s_r    = scr + 9360000;        // up to 12,329,280
  // phase3 aliases
  float* s_Qh = scr;                    // 1,040,000
  float* s_Kh = scr + 1040000;          // 1,040,000
  float* s_Vh = scr + 2080000;          // 1,560,000
  float* s_Vo = scr + 3640000;          // 1,560,000
  float* s_pj = scr + 5200000;          // 1,560,000
  // phase4 aliases
  float* s_pi = scr;                    // 12,480,000
  float* s_g  = scr + 12480000;         // 6,240,000

  const int thr = 256;
  auto cdiv = [](int a, int b){ return (a+b-1)/b; };

  // ---------------- Phase 1: intra (along Q) ----------------
  k_ln_chan<<<cdiv(2*250*65,thr), thr, 0, stream>>>(x, s_seq, intra_ng, intra_nb, 0);
  k_qkv<<<cdiv(500*65*144,thr), thr, 0, stream>>>(s_seq, af_in_w, af_in_b, s_qkv, 500*65);
  k_mha<<<dim3(500,4), 256, 0, stream>>>(s_qkv, s_att, 500, 65);
  k_projres<<<cdiv(500*65*48,thr), thr, 0, stream>>>(s_att, s_seq, af_out_w, af_out_b, s_seq2, 500*65);
  k_rowln<<<cdiv(32500,thr), thr, 0, stream>>>(s_seq2, naf_g, naf_b, 32500);
  k_wt<<<cdiv(147456,thr),thr,0,stream>>>(intra_wif, wT+0*147456);
  k_wt<<<cdiv(147456,thr),thr,0,stream>>>(intra_whf, wT+1*147456);
  k_wt<<<cdiv(147456,thr),thr,0,stream>>>(intra_wib, wT+2*147456);
  k_wt<<<cdiv(147456,thr),thr,0,stream>>>(intra_whb, wT+3*147456);
  k_lstm<<<dim3(125,2), 192, 0, stream>>>(s_seq2, s_r,
      wT+0*147456, wT+1*147456, intra_bif, intra_bhf,
      wT+2*147456, wT+3*147456, intra_bib, intra_bhb, 500, 62, 65);
  k_convt<<<cdiv(500*48*65,thr),thr,0,stream>>>(s_r, il_w, il_b, x, buf_intra, 500, 62, 65, 0);

  // ---------------- Phase 2: inter (along T) ----------------
  k_ln_chan<<<cdiv(2*250*65,thr),thr,0,stream>>>(buf_intra, s_seq, inter_ng, inter_nb, 1);
  k_qkv<<<cdiv(130*250*144,thr),thr,0,stream>>>(s_seq, at_in_w, at_in_b, s_qkv, 130*250);
  k_mha<<<dim3(130,4), 256, 0, stream>>>(s_qkv, s_att, 130, 250);
  k_projres<<<cdiv(130*250*48,thr),thr,0,stream>>>(s_att, s_seq, at_out_w, at_out_b, s_seq2, 130*250);
  k_rowln<<<cdiv(32500,thr),thr,0,stream>>>(s_seq2, nat_g, nat_b, 32500);
  k_wt<<<cdiv(147456,thr),thr,0,stream>>>(inter_wif, wT+4*147456);
  k_wt<<<cdiv(147456,thr),thr,0,stream>>>(inter_whf, wT+5*147456);
  k_wt<<<cdiv(147456,thr),thr,0,stream>>>(inter_wib, wT+6*147456);
  k_wt<<<cdiv(147456,thr),thr,0,stream>>>(inter_whb, wT+7*147456);
  k_lstm<<<dim3(33,2), 192, 0, stream>>>(s_seq2, s_r,
      wT+4*147456, wT+5*147456, inter_bif, inter_bhf,
      wT+6*147456, wT+7*147456, inter_bib, inter_bhb, 130, 247, 250);
  k_convt<<<cdiv(130*48*250,thr),thr,0,stream>>>(s_r, itl_w, itl_b, buf_intra, buf_bt, 130, 247, 250, 1);

  // ---------------- Phase 3: flattened-head attention ----------------
  k_headproj<<<cdiv(4*2*250*8*65,thr),thr,0,stream>>>(buf_bt, qw, qb, qa, s_Qh, 8);
  k_headln<<<2000,256,0,stream>>>(s_Qh, qg, qbt, 8);
  k_headproj<<<cdiv(4*2*250*8*65,thr),thr,0,stream>>>(buf_bt, kw, kb, ka, s_Kh, 8);
  k_headln<<<2000,256,0,stream>>>(s_Kh, kg, kbt, 8);
  k_headproj<<<cdiv(4*2*250*12*65,thr),thr,0,stream>>>(buf_bt, vw, vb, va, s_Vh, 12);
  k_headln<<<2000,256,0,stream>>>(s_Vh, vg, vbt, 12);
  k_headattn<<<2000,256,0,stream>>>(s_Qh, s_Kh, s_Vh, s_Vo);
  k_pproj<<<cdiv(2*48*250*65,thr),thr,0,stream>>>(s_Vo, pw, pb, pa, s_pj);
  k_pln<<<500,256,0,stream>>>(s_pj, pg, pbt, buf_bt, buf_out);

  // ---------------- Phase 4: FFN ----------------
  k_fin<<<cdiv(2*384*250*65,thr),thr,0,stream>>>(buf_out, fin_w, fin_b, s_pi);
  k_dwg<<<cdiv(2*192*250*65,thr),thr,0,stream>>>(s_pi, fdw_w, fdw_b, s_g);
  k_final<<<cdiv(2*48*250*65,thr),thr,0,stream>>>(s_g, fout_w, fout_b, buf_out, (float*)d_out);
}

// Round 2
// 5300.365 us; speedup vs baseline: 2.8687x; 2.8687x over previous
//
#include <hip/hip_runtime.h>
#include <math.h>

#define EPSV 1e-5f

typedef _Float16 v2h __attribute__((ext_vector_type(2)));

__device__ __forceinline__ float sigf(float x){ return 1.0f/(1.0f+expf(-x)); }

__device__ __forceinline__ float dot2u(unsigned int a, unsigned int b, float c){
#if __has_builtin(__builtin_amdgcn_fdot2)
  v2h av = __builtin_bit_cast(v2h, a);
  v2h bv = __builtin_bit_cast(v2h, b);
  return __builtin_amdgcn_fdot2(av, bv, c, false);
#else
  v2h av = __builtin_bit_cast(v2h, a);
  v2h bv = __builtin_bit_cast(v2h, b);
  return c + (float)av.x*(float)bv.x + (float)av.y*(float)bv.y;
#endif
}

// ---------------- LN over channel dim (ln_clamp, axes=(1,)) -> channel-last seq ----------------
__global__ void k_ln_chan(const float* __restrict__ src, float* __restrict__ dst,
                          const float* __restrict__ g, const float* __restrict__ bb, int mode){
  int i = blockIdx.x*blockDim.x + threadIdx.x;
  const int total = 2*250*65;
  if (i >= total) return;
  int q = i % 65; int t = (i/65) % 250; int b = i/(65*250);
  const float* p = src + (size_t)b*48*250*65 + (size_t)t*65 + q;
  float s=0.f, ss=0.f;
  for (int c=0;c<48;c++){ float v = p[(size_t)c*250*65]; s+=v; ss+=v*v; }
  float mu = s*(1.0f/48.0f);
  float var = ss*(1.0f/48.0f) - mu*mu;
  float rs = rsqrtf(fmaxf(var, EPSV));
  float* d = (mode==0) ? dst + ((size_t)(b*250+t)*65 + q)*48
                       : dst + ((size_t)(b*65+q)*250 + t)*48;
  for (int c=0;c<48;c++){ float v = p[(size_t)c*250*65]; d[c] = (v-mu)*rs*g[c] + bb[c]; }
}

// ---------------- qkv = seq @ in_w.T + in_b ----------------
__global__ void k_qkv(const float* __restrict__ seq, const float* __restrict__ w,
                      const float* __restrict__ bias, float* __restrict__ qkv, int NL){
  int i = blockIdx.x*blockDim.x + threadIdx.x;
  if (i >= NL*144) return;
  int j = i % 144; int nl = i / 144;
  const float* srow = seq + (size_t)nl*48;
  const float* wrow = w + j*48;
  float acc = bias[j];
  for (int c=0;c<48;c++) acc += srow[c]*wrow[c];
  qkv[i] = acc;
}

// ---------------- MHA core (per (n,h) block), dh=12, online softmax ----------------
__global__ void k_mha(const float* __restrict__ qkv, float* __restrict__ att, int N, int L){
  __shared__ float shq[250*12];
  __shared__ float shk[250*12];
  __shared__ float shv[250*12];
  int n = blockIdx.x, h = blockIdx.y;
  const float* base = qkv + (size_t)n*L*144 + h*12;
  for (int i = threadIdx.x; i < L*12; i += blockDim.x){
    int l = i/12, d = i%12;
    shq[i] = base[(size_t)l*144 + d];
    shk[i] = base[(size_t)l*144 + 48 + d];
    shv[i] = base[(size_t)l*144 + 96 + d];
  }
  __syncthreads();
  const float scale = 0.28867513459481287f;
  for (int r = threadIdx.x; r < L; r += blockDim.x){
    float m = -1e30f, den = 0.0f, o[12];
    for (int d=0; d<12; d++) o[d]=0.0f;
    const float* qr = shq + r*12;
    for (int j=0; j<L; j++){
      const float* kr = shk + j*12;
      float s = 0.f;
      for (int d=0; d<12; d++) s += qr[d]*kr[d];
      s *= scale;
      if (s > m){
        float corr = expf(m - s);
        den *= corr;
        for (int d=0; d<12; d++) o[d] *= corr;
        m = s;
      }
      float e = expf(s - m);
      den += e;
      const float* vr = shv + j*12;
      for (int d=0; d<12; d++) o[d] += e*vr[d];
    }
    float inv = 1.0f/den;
    float* outp = att + ((size_t)n*L + r)*48 + h*12;
    for (int d=0; d<12; d++) outp[d] = o[d]*inv;
  }
}

// ---------------- out proj + residual ----------------
__global__ void k_projres(const float* __restrict__ att, const float* __restrict__ seq,
                          const float* __restrict__ w, const float* __restrict__ bias,
                          float* __restrict__ dst, int NL){
  int i = blockIdx.x*blockDim.x + threadIdx.x;
  if (i >= NL*48) return;
  int o = i % 48; int nl = i/48;
  const float* ar = att + (size_t)nl*48;
  const float* wr = w + o*48;
  float acc = bias[o] + seq[i];
  for (int c=0;c<48;c++) acc += ar[c]*wr[c];
  dst[i] = acc;
}

// ---------------- torch_ln over last dim (48), in place ----------------
__global__ void k_rowln(float* __restrict__ buf, const float* __restrict__ g,
                        const float* __restrict__ bb, int NL){
  int nl = blockIdx.x*blockDim.x + threadIdx.x;
  if (nl >= NL) return;
  float* p = buf + (size_t)nl*48;
  float s=0.f, ss=0.f;
  for (int c=0;c<48;c++){ float v=p[c]; s+=v; ss+=v*v; }
  float mu = s*(1.0f/48.0f);
  float var = ss*(1.0f/48.0f) - mu*mu;
  float rs = rsqrtf(var + EPSV);
  for (int c=0;c<48;c++) p[c] = (p[c]-mu)*rs*g[c] + bb[c];
}

// ---------------- pack LSTM weight fp32 [768][192] -> half2-uint [96][768] ----------------
__global__ void k_wpack(const float* __restrict__ w, unsigned int* __restrict__ wp){
  int i = blockIdx.x*blockDim.x + threadIdx.x;
  if (i >= 96*768) return;
  int g = i % 768, d2 = i / 768;
  v2h v; v.x = (_Float16)w[g*192 + 2*d2]; v.y = (_Float16)w[g*192 + 2*d2 + 1];
  wp[(size_t)d2*768 + g] = __builtin_bit_cast(unsigned int, v);
}

// ---------------- transpose convT weight [384][48][4] -> [k][ii][c] ----------------
__global__ void k_wtc(const float* __restrict__ w, float* __restrict__ wt){
  int i = blockIdx.x*blockDim.x + threadIdx.x;
  if (i >= 4*384*48) return;
  int c = i % 48; int ii = (i/48) % 384; int k = i/(48*384);
  wt[i] = w[ii*192 + c*4 + k];
}

// ---------------- biLSTM scan v2: 256 thr = 3 gates/thr, G=4 seqs, f16 dot2 ----------------
__global__ __launch_bounds__(256) void k_lstm2(
    const float* __restrict__ seq2, float* __restrict__ r,
    const unsigned int* __restrict__ wpk_i_f, const unsigned int* __restrict__ wpk_h_f,
    const float* __restrict__ bi_f, const float* __restrict__ bh_f,
    const unsigned int* __restrict__ wpk_i_b, const unsigned int* __restrict__ wpk_h_b,
    const float* __restrict__ bi_b, const float* __restrict__ bh_b,
    int N, int L2, int SL){
  __shared__ unsigned int ush2[384];   // [d2][s] packed u pairs
  __shared__ unsigned int hh2[384];    // [d2][s] packed h pairs
  __shared__ float gsh[4*768];         // [s][gate]
  _Float16* hh2h = (_Float16*)hh2;

  int dir = blockIdx.y;
  int n0 = blockIdx.x*4;
  int t = threadIdx.x;
  const unsigned int* wi = dir ? wpk_i_b : wpk_i_f;
  const unsigned int* wh = dir ? wpk_h_b : wpk_h_f;
  const float* bi = dir ? bi_b : bi_f;
  const float* bh = dir ? bh_b : bh_f;
  float bsum0 = bi[t] + bh[t];
  float bsum1 = bi[t+256] + bh[t+256];
  float bsum2 = bi[t+512] + bh[t+512];
  float cst[4] = {0.f,0.f,0.f,0.f};
  for (int idx=t; idx<384; idx+=256) hh2[idx] = 0u;

  for (int step=0; step<L2; step++){
    int l = dir ? (L2-1-step) : step;
    // load & pack u
    for (int idx=t; idx<384; idx+=256){
      int s = idx & 3, d2 = idx >> 2;
      int c = d2 >> 1, k0 = (d2 & 1)*2;
      float u0=0.f, u1=0.f;
      if (n0+s < N){
        const float* p = seq2 + ((size_t)(n0+s)*SL + l)*48;
        u0 = p[k0*48 + c];
        u1 = p[(k0+1)*48 + c];
      }
      v2h v; v.x = (_Float16)u0; v.y = (_Float16)u1;
      ush2[idx] = __builtin_bit_cast(unsigned int, v);
    }
    __syncthreads();

    float a0_0=bsum0,a0_1=bsum0,a0_2=bsum0,a0_3=bsum0;
    float a1_0=bsum1,a1_1=bsum1,a1_2=bsum1,a1_3=bsum1;
    float a2_0=bsum2,a2_1=bsum2,a2_2=bsum2,a2_3=bsum2;
    const uint4* uv = (const uint4*)ush2;
    const uint4* hv = (const uint4*)hh2;
    #pragma unroll 4
    for (int d2=0; d2<96; d2++){
      uint4 uu = uv[d2];
      uint4 hh = hv[d2];
      unsigned int wi0 = wi[(size_t)d2*768 + t];
      unsigned int wi1 = wi[(size_t)d2*768 + t + 256];
      unsigned int wi2 = wi[(size_t)d2*768 + t + 512];
      unsigned int wh0 = wh[(size_t)d2*768 + t];
      unsigned int wh1 = wh[(size_t)d2*768 + t + 256];
      unsigned int wh2 = wh[(size_t)d2*768 + t + 512];
      a0_0 = dot2u(uu.x, wi0, a0_0); a0_0 = dot2u(hh.x, wh0, a0_0);
      a0_1 = dot2u(uu.y, wi0, a0_1); a0_1 = dot2u(hh.y, wh0, a0_1);
      a0_2 = dot2u(uu.z, wi0, a0_2); a0_2 = dot2u(hh.z, wh0, a0_2);
      a0_3 = dot2u(uu.w, wi0, a0_3); a0_3 = dot2u(hh.w, wh0, a0_3);
      a1_0 = dot2u(uu.x, wi1, a1_0); a1_0 = dot2u(hh.x, wh1, a1_0);
      a1_1 = dot2u(uu.y, wi1, a1_1); a1_1 = dot2u(hh.y, wh1, a1_1);
      a1_2 = dot2u(uu.z, wi1, a1_2); a1_2 = dot2u(hh.z, wh1, a1_2);
      a1_3 = dot2u(uu.w, wi1, a1_3); a1_3 = dot2u(hh.w, wh1, a1_3);
      a2_0 = dot2u(uu.x, wi2, a2_0); a2_0 = dot2u(hh.x, wh2, a2_0);
      a2_1 = dot2u(uu.y, wi2, a2_1); a2_1 = dot2u(hh.y, wh2, a2_1);
      a2_2 = dot2u(uu.z, wi2, a2_2); a2_2 = dot2u(hh.z, wh2, a2_2);
      a2_3 = dot2u(uu.w, wi2, a2_3); a2_3 = dot2u(hh.w, wh2, a2_3);
    }
    gsh[0*768 + t] = a0_0; gsh[1*768 + t] = a0_1; gsh[2*768 + t] = a0_2; gsh[3*768 + t] = a0_3;
    gsh[0*768 + 256 + t] = a1_0; gsh[1*768 + 256 + t] = a1_1; gsh[2*768 + 256 + t] = a1_2; gsh[3*768 + 256 + t] = a1_3;
    gsh[0*768 + 512 + t] = a2_0; gsh[1*768 + 512 + t] = a2_1; gsh[2*768 + 512 + t] = a2_2; gsh[3*768 + 512 + t] = a2_3;
    __syncthreads();

    if (t < 192){
      int j = t;
      for (int s=0; s<4; s++){
        float ig = sigf(gsh[s*768 + j]);
        float fg = sigf(gsh[s*768 + 192 + j]);
        float gg = tanhf(gsh[s*768 + 384 + j]);
        float og = sigf(gsh[s*768 + 576 + j]);
        cst[s] = fg*cst[s] + ig*gg;
        float hn = og*tanhf(cst[s]);
        if (n0+s < N) r[((size_t)(n0+s)*L2 + l)*384 + dir*192 + j] = hn;
        hh2h[(j>>1)*8 + s*2 + (j&1)] = (_Float16)hn;
      }
    }
    __syncthreads();
  }
}

// ---------------- conv_transpose1d v2: block per (n, 64-pos tile), W_k staged in LDS ----------
__global__ __launch_bounds__(256) void k_convt2(
    const float* __restrict__ r, const float* __restrict__ wt2,
    const float* __restrict__ bias, const float* __restrict__ resid,
    float* __restrict__ dst, int L2, int OL, int mode){
  __shared__ float wsh[384*48];
  int n = blockIdx.y;
  int p0 = blockIdx.x*64;
  int tid = threadIdx.x;
  int pos = p0 + (tid >> 2);
  int cq = tid & 3;              // c = cq*12 .. +11
  float4 acc[3];
  acc[0] = make_float4(0,0,0,0); acc[1] = make_float4(0,0,0,0); acc[2] = make_float4(0,0,0,0);

  for (int k=0; k<4; k++){
    const float4* wk4 = (const float4*)(wt2 + (size_t)k*384*48);
    float4* wsh4 = (float4*)wsh;
    for (int i=tid; i<4608; i+=256) wsh4[i] = wk4[i];
    __syncthreads();
    int l = pos - k;
    if (l >= 0 && l < L2){
      const float4* rr = (const float4*)(r + ((size_t)n*L2 + l)*384);
      const float4* wb = (const float4*)(wsh + cq*12);
      #pragma unroll 4
      for (int ii4=0; ii4<96; ii4++){
        float4 rv = rr[ii4];
        const float4* w0 = wb + (ii4*4)*12;      // float4 stride: 48 floats = 12 float4
        float4 wa, wbv, wc;
        wa = w0[0]; wbv = w0[1]; wc = w0[2];
        acc[0].x += rv.x*wa.x; acc[0].y += rv.x*wa.y; acc[0].z += rv.x*wa.z; acc[0].w += rv.x*wa.w;
        acc[1].x += rv.x*wbv.x; acc[1].y += rv.x*wbv.y; acc[1].z += rv.x*wbv.z; acc[1].w += rv.x*wbv.w;
        acc[2].x += rv.x*wc.x; acc[2].y += rv.x*wc.y; acc[2].z += rv.x*wc.z; acc[2].w += rv.x*wc.w;
        wa = w0[12]; wbv = w0[13]; wc = w0[14];
        acc[0].x += rv.y*wa.x; acc[0].y += rv.y*wa.y; acc[0].z += rv.y*wa.z; acc[0].w += rv.y*wa.w;
        acc[1].x += rv.y*wbv.x; acc[1].y += rv.y*wbv.y; acc[1].z += rv.y*wbv.z; acc[1].w += rv.y*wbv.w;
        acc[2].x += rv.y*wc.x; acc[2].y += rv.y*wc.y; acc[2].z += rv.y*wc.z; acc[2].w += rv.y*wc.w;
        wa = w0[24]; wbv = w0[25]; wc = w0[26];
        acc[0].x += rv.z*wa.x; acc[0].y += rv.z*wa.y; acc[0].z += rv.z*wa.z; acc[0].w += rv.z*wa.w;
        acc[1].x += rv.z*wbv.x; acc[1].y += rv.z*wbv.y; acc[1].z += rv.z*wbv.z; acc[1].w += rv.z*wbv.w;
        acc[2].x += rv.z*wc.x; acc[2].y += rv.z*wc.y; acc[2].z += rv.z*wc.z; acc[2].w += rv.z*wc.w;
        wa = w0[36]; wbv = w0[37]; wc = w0[38];
        acc[0].x += rv.w*wa.x; acc[0].y += rv.w*wa.y; acc[0].z += rv.w*wa.z; acc[0].w += rv.w*wa.w;
        acc[1].x += rv.w*wbv.x; acc[1].y += rv.w*wbv.y; acc[1].z += rv.w*wbv.z; acc[1].w += rv.w*wbv.w;
        acc[2].x += rv.w*wc.x; acc[2].y += rv.w*wc.y; acc[2].z += rv.w*wc.z; acc[2].w += rv.w*wc.w;
      }
    }
    __syncthreads();
  }

  if (pos < OL){
    float a[12];
    a[0]=acc[0].x; a[1]=acc[0].y; a[2]=acc[0].z; a[3]=acc[0].w;
    a[4]=acc[1].x; a[5]=acc[1].y; a[6]=acc[1].z; a[7]=acc[1].w;
    a[8]=acc[2].x; a[9]=acc[2].y; a[10]=acc[2].z; a[11]=acc[2].w;
    for (int c12=0; c12<12; c12++){
      int c = cq*12 + c12;
      size_t oidx;
      if (mode==0){ int b = n/250, t = n%250; oidx = (((size_t)b*48+c)*250+t)*65 + pos; }
      else        { int b = n/65,  q = n%65;  oidx = (((size_t)b*48+c)*250+pos)*65 + q; }
      dst[oidx] = a[c12] + bias[c] + resid[oidx];
    }
  }
}

// ---------------- head projection + per-head leaky ----------------
__global__ void k_headproj(const float* __restrict__ bt, const float* __restrict__ w,
                           const float* __restrict__ bias, const float* __restrict__ alpha,
                           float* __restrict__ dst, int dim){
  int i = blockIdx.x*blockDim.x + threadIdx.x;
  int total = 4*2*250*dim*65;
  if (i >= total) return;
  int f = i % 65;
  int e = (i/65) % dim;
  int t = (i/(65*dim)) % 250;
  int b = (i/(65*dim*250)) % 2;
  int h = i/(65*dim*250*2);
  const float* wr = w + (h*dim+e)*48;
  const float* bp = bt + (size_t)b*48*250*65 + (size_t)t*65 + f;
  float acc = bias[h*dim+e];
  for (int c=0;c<48;c++) acc += bp[(size_t)c*250*65]*wr[c];
  if (acc < 0.f) acc *= alpha[h];
  dst[i] = acc;
}

// ---------------- ln_clamp over (e,f) per (h,b,t) block, in place ----------------
__global__ void k_headln(float* __restrict__ buf, const float* __restrict__ g,
                         const float* __restrict__ bt_, int dim){
  __shared__ float r1[256];
  __shared__ float r2[256];
  int bx = blockIdx.x;
  int h = bx/500;
  int n = dim*65;
  float* p = buf + (size_t)bx*n;
  const float* gp = g + h*n;
  const float* bp = bt_ + h*n;
  float s=0.f, ss=0.f;
  for (int k=threadIdx.x; k<n; k+=256){ float v=p[k]; s+=v; ss+=v*v; }
  r1[threadIdx.x]=s; r2[threadIdx.x]=ss; __syncthreads();
  for (int st=128; st>0; st>>=1){
    if (threadIdx.x < st){ r1[threadIdx.x]+=r1[threadIdx.x+st]; r2[threadIdx.x]+=r2[threadIdx.x+st]; }
    __syncthreads();
  }
  float mu = r1[0]/(float)n, var = r2[0]/(float)n - mu*mu;
  float rs = rsqrtf(fmaxf(var, EPSV));
  for (int k=threadIdx.x; k<n; k+=256) p[k] = (p[k]-mu)*rs*gp[k] + bp[k];
}

// ---------------- flattened-head attention: block per (h,b,t) ----------------
__global__ void k_headattn(const float* __restrict__ Qp, const float* __restrict__ Kp,
                           const float* __restrict__ Vp, float* __restrict__ Vo){
  __shared__ float qsh[520];
  __shared__ float psh[250];
  __shared__ float r1[256];
  int bx = blockIdx.x;
  int t = bx % 250;
  int b = (bx/250) % 2;
  int h = bx/500;
  int hb = h*2 + b;
  const float* qrow = Qp + ((size_t)hb*250 + t)*520;
  for (int d=threadIdx.x; d<520; d+=256) qsh[d] = qrow[d];
  __syncthreads();
  const float scale = rsqrtf(520.0f);
  float lmax = -1e30f;
  for (int s2=threadIdx.x; s2<250; s2+=256){
    const float* kr = Kp + ((size_t)hb*250 + s2)*520;
    float acc = 0.f;
    for (int d=0; d<520; d++) acc += qsh[d]*kr[d];
    acc *= scale;
    psh[s2] = acc;
    lmax = fmaxf(lmax, acc);
  }
  r1[threadIdx.x] = lmax; __syncthreads();
  for (int st=128; st>0; st>>=1){
    if (threadIdx.x<st) r1[threadIdx.x]=fmaxf(r1[threadIdx.x], r1[threadIdx.x+st]);
    __syncthreads();
  }
  float m = r1[0];
  __syncthreads();
  float lsum = 0.f;
  for (int s2=threadIdx.x; s2<250; s2+=256){
    float e = expf(psh[s2]-m);
    psh[s2] = e;
    lsum += e;
  }
  r1[threadIdx.x]=lsum; __syncthreads();
  for (int st=128; st>0; st>>=1){
    if (threadIdx.x<st) r1[threadIdx.x]+=r1[threadIdx.x+st];
    __syncthreads();
  }
  float inv = 1.0f/r1[0];
  for (int d=threadIdx.x; d<780; d+=256){
    float acc = 0.f;
    const float* vcol = Vp + (size_t)hb*250*780 + d;
    for (int s2=0; s2<250; s2++) acc += psh[s2]*vcol[(size_t)s2*780];
    acc *= inv;
    int e = d/65, f = d%65;
    Vo[(((size_t)b*48 + h*12 + e)*250 + t)*65 + f] = acc;
  }
}

// ---------------- p-projection + leaky (scalar alpha) ----------------
__global__ void k_pproj(const float* __restrict__ Vo, const float* __restrict__ pw,
                        const float* __restrict__ pb, const float* __restrict__ pa,
                        float* __restrict__ pj){
  int i = blockIdx.x*blockDim.x + threadIdx.x;
  if (i >= 2*48*250*65) return;
  int f = i % 65;
  int t = (i/65) % 250;
  int o = (i/(65*250)) % 48;
  int b = i/(65*250*48);
  const float* vp = Vo + (size_t)b*48*250*65 + (size_t)t*65 + f;
  const float* wr = pw + o*48;
  float acc = pb[o];
  for (int c=0;c<48;c++) acc += vp[(size_t)c*250*65]*wr[c];
  if (acc < 0.f) acc *= pa[0];
  pj[i] = acc;
}

// ---------------- ln_clamp over (c,f) per (b,t) + residual(inter) ----------------
__global__ void k_pln(const float* __restrict__ pj, const float* __restrict__ pg,
                      const float* __restrict__ pbt, const float* __restrict__ inter,
                      float* __restrict__ outb){
  __shared__ float r1[256];
  __shared__ float r2[256];
  int bx = blockIdx.x;
  int t = bx % 250, b = bx/250;
  const float* base = pj + (size_t)b*48*250*65 + (size_t)t*65;
  float s=0.f, ss=0.f;
  for (int k=threadIdx.x; k<3120; k+=256){
    int c = k/65, f = k%65;
    float v = base[(size_t)c*250*65 + f];
    s+=v; ss+=v*v;
  }
  r1[threadIdx.x]=s; r2[threadIdx.x]=ss; __syncthreads();
  for (int st=128; st>0; st>>=1){
    if (threadIdx.x<st){ r1[threadIdx.x]+=r1[threadIdx.x+st]; r2[threadIdx.x]+=r2[threadIdx.x+st]; }
    __syncthreads();
  }
  float mu = r1[0]*(1.0f/3120.0f), var = r2[0]*(1.0f/3120.0f) - mu*mu;
  float rs = rsqrtf(fmaxf(var, EPSV));
  for (int k=threadIdx.x; k<3120; k+=256){
    int c = k/65, f = k%65;
    size_t idx = (((size_t)b*48+c)*250 + t)*65 + f;
    float v = pj[idx];
    outb[idx] = (v-mu)*rs*pg[c*65+f] + pbt[c*65+f] + inter[idx];
  }
}

// ---------------- fin 1x1: (B,48,...) -> (B,384,...) ----------------
__global__ void k_fin(const float* __restrict__ outb, const float* __restrict__ w,
                      const float* __restrict__ bias, float* __restrict__ pi){
  int i = blockIdx.x*blockDim.x + threadIdx.x;
  if (i >= 2*384*250*65) return;
  int f = i % 65;
  int t = (i/65) % 250;
  int o = (i/(65*250)) % 384;
  int b = i/(65*250*384);
  const float* xp = outb + (size_t)b*48*250*65 + (size_t)t*65 + f;
  const float* wr = w + o*48;
  float acc = bias[o];
  for (int c=0;c<48;c++) acc += xp[(size_t)c*250*65]*wr[c];
  pi[i] = acc;
}

// ---------------- fused depthwise 3x3 (pad 1) on both halves + gelu-gate ----------------
__global__ void k_dwg(const float* __restrict__ pi, const float* __restrict__ dw,
                      const float* __restrict__ db, float* __restrict__ gbuf){
  int i = blockIdx.x*blockDim.x + threadIdx.x;
  if (i >= 2*192*250*65) return;
  int f = i % 65;
  int t = (i/65) % 250;
  int j = (i/(65*250)) % 192;
  int b = i/(65*250*192);
  float x12[2];
  for (int half=0; half<2; half++){
    int ch = j + half*192;
    const float* base = pi + ((size_t)b*384 + ch)*250*65;
    const float* wr = dw + ch*9;
    float acc = db[ch];
    for (int dt=-1; dt<=1; dt++){
      int tt = t+dt;
      if (tt<0||tt>=250) continue;
      for (int df=-1; df<=1; df++){
        int ff = f+df;
        if (ff<0||ff>=65) continue;
        acc += base[(size_t)tt*65+ff]*wr[(dt+1)*3 + (df+1)];
      }
    }
    x12[half]=acc;
  }
  float x1 = x12[0];
  float g = 0.5f*x1*(1.0f+erff(x1*0.70710678118654752f));
  gbuf[i] = g * x12[1];
}

// ---------------- final 1x1 (192->48) + residual -> d_out ----------------
__global__ void k_final(const float* __restrict__ gbuf, const float* __restrict__ w,
                        const float* __restrict__ bias, const float* __restrict__ outb,
                        float* __restrict__ dout){
  int i = blockIdx.x*blockDim.x + threadIdx.x;
  if (i >= 2*48*250*65) return;
  int f = i % 65;
  int t = (i/65) % 250;
  int o = (i/(65*250)) % 48;
  int b = i/(65*250*48);
  const float* gp = gbuf + (size_t)b*192*250*65 + (size_t)t*65 + f;
  const float* wr = w + o*192;
  float acc = bias[o];
  for (int j=0;j<192;j++) acc += gp[(size_t)j*250*65]*wr[j];
  dout[i] = acc + outb[i];
}

extern "C" void kernel_launch(void* const* d_in, const int* in_sizes, int n_in,
                              void* d_out, int out_size, void* d_ws, size_t ws_size,
                              hipStream_t stream) {
  (void)in_sizes; (void)n_in; (void)out_size; (void)ws_size;
  auto in = [&](int i){ return (const float*)d_in[i]; };
  const float* x        = in(0);
  const float* af_in_w  = in(1);  const float* af_in_b  = in(2);
  const float* af_out_w = in(3);  const float* af_out_b = in(4);
  const float* at_in_w  = in(5);  const float* at_in_b  = in(6);
  const float* at_out_w = in(7);  const float* at_out_b = in(8);
  const float* naf_g = in(9),  *naf_b = in(10), *nat_g = in(11), *nat_b = in(12);
  const float* intra_ng = in(13), *intra_nb = in(14), *inter_ng = in(15), *inter_nb = in(16);
  const float* intra_wif = in(17), *intra_whf = in(18), *intra_bif = in(19), *intra_bhf = in(20);
  const float* intra_wib = in(21), *intra_whb = in(22), *intra_bib = in(23), *intra_bhb = in(24);
  const float* inter_wif = in(25), *inter_whf = in(26), *inter_bif = in(27), *inter_bhf = in(28);
  const float* inter_wib = in(29), *inter_whb = in(30), *inter_bib = in(31), *inter_bhb = in(32);
  const float* il_w = in(33), *il_b = in(34), *itl_w = in(35), *itl_b = in(36);
  const float* qw = in(37), *qb = in(38), *qa = in(39), *qg = in(40), *qbt = in(41);
  const float* kw = in(42), *kb = in(43), *ka = in(44), *kg = in(45), *kbt = in(46);
  const float* vw = in(47), *vb = in(48), *va = in(49), *vg = in(50), *vbt = in(51);
  const float* pw = in(52), *pb = in(53), *pa = in(54), *pg = in(55), *pbt = in(56);
  const float* fin_w = in(57), *fin_b = in(58), *fdw_w = in(59), *fdw_b = in(60);
  const float* fout_w = in(61), *fout_b = in(62);

  float* ws = (float*)d_ws;
  float* buf_intra = ws + 0;            // 1,560,000
  float* buf_bt    = ws + 1560000;      // 1,560,000
  float* buf_out   = ws + 3120000;      // 1,560,000
  unsigned int* wpk = (unsigned int*)(ws + 4680000);   // 8 * 73,728 uints
  float* wtc       = ws + 5269824;      // 2 * 73,728 floats
  float* scr       = ws + 5420000;      // scratch arena
  float* s_seq  = scr;                  // 1,560,000
  float* s_qkv  = scr + 1560000;        // 4,680,000
  float* s_att  = scr + 6240000;        // 1,560,000
  float* s_seq2 = scr + 7800000;        // 1,560,000
  float* s_r    = scr + 9360000;        // up to 12,329,280
  // phase3 aliases
  float* s_Qh = scr;
  float* s_Kh = scr + 1040000;
  float* s_Vh = scr + 2080000;
  float* s_Vo = scr + 3640000;
  float* s_pj = scr + 5200000;
  // phase4 aliases
  float* s_pi = scr;
  float* s_g  = scr + 12480000;

  const int thr = 256;
  auto cdiv = [](int a, int b){ return (a+b-1)/b; };

  // ---------------- weight prep (all phases) ----------------
  k_wpack<<<cdiv(73728,thr),thr,0,stream>>>(intra_wif, wpk + 0*73728);
  k_wpack<<<cdiv(73728,thr),thr,0,stream>>>(intra_whf, wpk + 1*73728);
  k_wpack<<<cdiv(73728,thr),thr,0,stream>>>(intra_wib, wpk + 2*73728);
  k_wpack<<<cdiv(73728,thr),thr,0,stream>>>(intra_whb, wpk + 3*73728);
  k_wpack<<<cdiv(73728,thr),thr,0,stream>>>(inter_wif, wpk + 4*73728);
  k_wpack<<<cdiv(73728,thr),thr,0,stream>>>(inter_whf, wpk + 5*73728);
  k_wpack<<<cdiv(73728,thr),thr,0,stream>>>(inter_wib, wpk + 6*73728);
  k_wpack<<<cdiv(73728,thr),thr,0,stream>>>(inter_whb, wpk + 7*73728);
  k_wtc<<<cdiv(73728,thr),thr,0,stream>>>(il_w,  wtc + 0*73728);
  k_wtc<<<cdiv(73728,thr),thr,0,stream>>>(itl_w, wtc + 1*73728);

  // ---------------- Phase 1: intra (along Q) ----------------
  k_ln_chan<<<cdiv(2*250*65,thr), thr, 0, stream>>>(x, s_seq, intra_ng, intra_nb, 0);
  k_qkv<<<cdiv(500*65*144,thr), thr, 0, stream>>>(s_seq, af_in_w, af_in_b, s_qkv, 500*65);
  k_mha<<<dim3(500,4), 256, 0, stream>>>(s_qkv, s_att, 500, 65);
  k_projres<<<cdiv(500*65*48,thr), thr, 0, stream>>>(s_att, s_seq, af_out_w, af_out_b, s_seq2, 500*65);
  k_rowln<<<cdiv(32500,thr), thr, 0, stream>>>(s_seq2, naf_g, naf_b, 32500);
  k_lstm2<<<dim3(125,2), 256, 0, stream>>>(s_seq2, s_r,
      wpk+0*73728, wpk+1*73728, intra_bif, intra_bhf,
      wpk+2*73728, wpk+3*73728, intra_bib, intra_bhb, 500, 62, 65);
  k_convt2<<<dim3(2,500), 256, 0, stream>>>(s_r, wtc+0*73728, il_b, x, buf_intra, 62, 65, 0);

  // ---------------- Phase 2: inter (along T) ----------------
  k_ln_chan<<<cdiv(2*250*65,thr),thr,0,stream>>>(buf_intra, s_seq, inter_ng, inter_nb, 1);
  k_qkv<<<cdiv(130*250*144,thr),thr,0,stream>>>(s_seq, at_in_w, at_in_b, s_qkv, 130*250);
  k_mha<<<dim3(130,4), 256, 0, stream>>>(s_qkv, s_att, 130, 250);
  k_projres<<<cdiv(130*250*48,thr),thr,0,stream>>>(s_att, s_seq, at_out_w, at_out_b, s_seq2, 130*250);
  k_rowln<<<cdiv(32500,thr),thr,0,stream>>>(s_seq2, nat_g, nat_b, 32500);
  k_lstm2<<<dim3(33,2), 256, 0, stream>>>(s_seq2, s_r,
      wpk+4*73728, wpk+5*73728, inter_bif, inter_bhf,
      wpk+6*73728, wpk+7*73728, inter_bib, inter_bhb, 130, 247, 250);
  k_convt2<<<dim3(4,130), 256, 0, stream>>>(s_r, wtc+1*73728, itl_b, buf_intra, buf_bt, 247, 250, 1);

  // ---------------- Phase 3: flattened-head attention ----------------
  k_headproj<<<cdiv(4*2*250*8*65,thr),thr,0,stream>>>(buf_bt, qw, qb, qa, s_Qh, 8);
  k_headln<<<2000,256,0,stream>>>(s_Qh, qg, qbt, 8);
  k_headproj<<<cdiv(4*2*250*8*65,thr),thr,0,stream>>>(buf_bt, kw, kb, ka, s_Kh, 8);
  k_headln<<<2000,256,0,stream>>>(s_Kh, kg, kbt, 8);
  k_headproj<<<cdiv(4*2*250*12*65,thr),thr,0,stream>>>(buf_bt, vw, vb, va, s_Vh, 12);
  k_headln<<<2000,256,0,stream>>>(s_Vh, vg, vbt, 12);
  k_headattn<<<2000,256,0,stream>>>(s_Qh, s_Kh, s_Vh, s_Vo);
  k_pproj<<<cdiv(2*48*250*65,thr),thr,0,stream>>>(s_Vo, pw, pb, pa, s_pj);
  k_pln<<<500,256,0,stream>>>(s_pj, pg, pbt, buf_bt, buf_out);

  // ---------------- Phase 4: FFN ----------------
  k_fin<<<cdiv(2*384*250*65,thr),thr,0,stream>>>(buf_out, fin_w, fin_b, s_pi);
  k_dwg<<<cdiv(2*192*250*65,thr),thr,0,stream>>>(s_pi, fdw_w, fdw_b, s_g);
  k_final<<<cdiv(2*48*250*65,thr),thr,0,stream>>>(s_g, fout_w, fout_b, buf_out, (float*)d_out);
}

// Round 3
// 3420.326 us; speedup vs baseline: 4.4455x; 1.5497x over previous
//
#include <hip/hip_runtime.h>
#include <math.h>

#define EPSV 1e-5f

typedef _Float16 v2h __attribute__((ext_vector_type(2)));

__device__ __forceinline__ float sigf(float x){ return 1.0f/(1.0f+__expf(-x)); }
__device__ __forceinline__ float tanhf_(float x){
  float c = fminf(fmaxf(x,-10.f),10.f);
  float e = __expf(2.0f*c);
  return (e-1.0f)/(e+1.0f);
}

__device__ __forceinline__ float dot2u(unsigned int a, unsigned int b, float c){
#if __has_builtin(__builtin_amdgcn_fdot2)
  v2h av = __builtin_bit_cast(v2h, a);
  v2h bv = __builtin_bit_cast(v2h, b);
  return __builtin_amdgcn_fdot2(av, bv, c, false);
#else
  v2h av = __builtin_bit_cast(v2h, a);
  v2h bv = __builtin_bit_cast(v2h, b);
  return c + (float)av.x*(float)bv.x + (float)av.y*(float)bv.y;
#endif
}

// ---------------- LN over channel dim -> channel-last seq ----------------
__global__ void k_ln_chan(const float* __restrict__ src, float* __restrict__ dst,
                          const float* __restrict__ g, const float* __restrict__ bb, int mode){
  int i = blockIdx.x*blockDim.x + threadIdx.x;
  const int total = 2*250*65;
  if (i >= total) return;
  int q = i % 65; int t = (i/65) % 250; int b = i/(65*250);
  const float* p = src + (size_t)b*48*250*65 + (size_t)t*65 + q;
  float s=0.f, ss=0.f;
  for (int c=0;c<48;c++){ float v = p[(size_t)c*250*65]; s+=v; ss+=v*v; }
  float mu = s*(1.0f/48.0f);
  float var = ss*(1.0f/48.0f) - mu*mu;
  float rs = rsqrtf(fmaxf(var, EPSV));
  float* d = (mode==0) ? dst + ((size_t)(b*250+t)*65 + q)*48
                       : dst + ((size_t)(b*65+q)*250 + t)*48;
  for (int c=0;c<48;c++){ float v = p[(size_t)c*250*65]; d[c] = (v-mu)*rs*g[c] + bb[c]; }
}

// ---------------- qkv = seq @ in_w.T + in_b ----------------
__global__ void k_qkv(const float* __restrict__ seq, const float* __restrict__ w,
                      const float* __restrict__ bias, float* __restrict__ qkv, int NL){
  int i = blockIdx.x*blockDim.x + threadIdx.x;
  if (i >= NL*144) return;
  int j = i % 144; int nl = i / 144;
  const float* srow = seq + (size_t)nl*48;
  const float* wrow = w + j*48;
  float acc = bias[j];
  for (int c=0;c<48;c++) acc += srow[c]*wrow[c];
  qkv[i] = acc;
}

// ---------------- MHA core ----------------
__global__ void k_mha(const float* __restrict__ qkv, float* __restrict__ att, int N, int L){
  __shared__ float shq[250*12];
  __shared__ float shk[250*12];
  __shared__ float shv[250*12];
  int n = blockIdx.x, h = blockIdx.y;
  const float* base = qkv + (size_t)n*L*144 + h*12;
  for (int i = threadIdx.x; i < L*12; i += blockDim.x){
    int l = i/12, d = i%12;
    shq[i] = base[(size_t)l*144 + d];
    shk[i] = base[(size_t)l*144 + 48 + d];
    shv[i] = base[(size_t)l*144 + 96 + d];
  }
  __syncthreads();
  const float scale = 0.28867513459481287f;
  for (int r = threadIdx.x; r < L; r += blockDim.x){
    float m = -1e30f, den = 0.0f, o[12];
    for (int d=0; d<12; d++) o[d]=0.0f;
    const float* qr = shq + r*12;
    for (int j=0; j<L; j++){
      const float* kr = shk + j*12;
      float s = 0.f;
      for (int d=0; d<12; d++) s += qr[d]*kr[d];
      s *= scale;
      if (s > m){
        float corr = __expf(m - s);
        den *= corr;
        for (int d=0; d<12; d++) o[d] *= corr;
        m = s;
      }
      float e = __expf(s - m);
      den += e;
      const float* vr = shv + j*12;
      for (int d=0; d<12; d++) o[d] += e*vr[d];
    }
    float inv = 1.0f/den;
    float* outp = att + ((size_t)n*L + r)*48 + h*12;
    for (int d=0; d<12; d++) outp[d] = o[d]*inv;
  }
}

// ---------------- out proj + residual ----------------
__global__ void k_projres(const float* __restrict__ att, const float* __restrict__ seq,
                          const float* __restrict__ w, const float* __restrict__ bias,
                          float* __restrict__ dst, int NL){
  int i = blockIdx.x*blockDim.x + threadIdx.x;
  if (i >= NL*48) return;
  int o = i % 48; int nl = i/48;
  const float* ar = att + (size_t)nl*48;
  const float* wr = w + o*48;
  float acc = bias[o] + seq[i];
  for (int c=0;c<48;c++) acc += ar[c]*wr[c];
  dst[i] = acc;
}

// ---------------- torch_ln over last dim (48), in place ----------------
__global__ void k_rowln(float* __restrict__ buf, const float* __restrict__ g,
                        const float* __restrict__ bb, int NL){
  int nl = blockIdx.x*blockDim.x + threadIdx.x;
  if (nl >= NL) return;
  float* p = buf + (size_t)nl*48;
  float s=0.f, ss=0.f;
  for (int c=0;c<48;c++){ float v=p[c]; s+=v; ss+=v*v; }
  float mu = s*(1.0f/48.0f);
  float var = ss*(1.0f/48.0f) - mu*mu;
  float rs = rsqrtf(var + EPSV);
  for (int c=0;c<48;c++) p[c] = (p[c]-mu)*rs*g[c] + bb[c];
}

// ---------------- pack LSTM weight fp32 [768][192] -> half2-uint [96][768] ----------------
__global__ void k_wpack(const float* __restrict__ w, unsigned int* __restrict__ wp){
  int i = blockIdx.x*blockDim.x + threadIdx.x;
  if (i >= 96*768) return;
  int g = i % 768, d2 = i / 768;
  v2h v; v.x = (_Float16)w[g*192 + 2*d2]; v.y = (_Float16)w[g*192 + 2*d2 + 1];
  wp[(size_t)d2*768 + g] = __builtin_bit_cast(unsigned int, v);
}

// ---------------- transpose convT weight [384][48][4] -> [k][ii][c] ----------------
__global__ void k_wtc(const float* __restrict__ w, float* __restrict__ wt){
  int i = blockIdx.x*blockDim.x + threadIdx.x;
  if (i >= 4*384*48) return;
  int c = i % 48; int ii = (i/48) % 384; int k = i/(48*384);
  wt[i] = w[ii*192 + c*4 + k];
}

// ---------------- pre-gates GEMM: pre[n][l][g] = u.wi^T + bi + bh (f16 out) ----------------
// grid (ceil(L2/16), N), 256 threads; each thread 3 gates x 16 l.
__global__ __launch_bounds__(256) void k_pregates(
    const float* __restrict__ seq2, const unsigned int* __restrict__ wi,
    const float* __restrict__ bi, const float* __restrict__ bh,
    _Float16* __restrict__ pre, int L2, int SL){
  __shared__ unsigned int ut[96*16];   // [d2][l]
  int n = blockIdx.y;
  int l0 = blockIdx.x*16;
  int t = threadIdx.x;
  for (int idx=t; idx<1536; idx+=256){
    int l = idx & 15, d2 = idx >> 4;
    int li = l0 + l;
    int c = d2 >> 1, k0 = (d2 & 1)*2;
    float u0=0.f, u1=0.f;
    if (li < L2){
      const float* p = seq2 + ((size_t)n*SL + li)*48;
      u0 = p[k0*48 + c];
      u1 = p[(k0+1)*48 + c];
    }
    v2h v; v.x=(_Float16)u0; v.y=(_Float16)u1;
    ut[d2*16 + l] = __builtin_bit_cast(unsigned int, v);
  }
  __syncthreads();
  float acc[3][16];
  float b0 = bi[t] + bh[t];
  float b1 = bi[t+256] + bh[t+256];
  float b2 = bi[t+512] + bh[t+512];
  #pragma unroll
  for (int l=0;l<16;l++){ acc[0][l]=b0; acc[1][l]=b1; acc[2][l]=b2; }
  #pragma unroll 4
  for (int d2=0; d2<96; d2++){
    unsigned int w0 = wi[(size_t)d2*768 + t];
    unsigned int w1 = wi[(size_t)d2*768 + t + 256];
    unsigned int w2 = wi[(size_t)d2*768 + t + 512];
    const uint4* u4 = (const uint4*)(ut + d2*16);
    #pragma unroll
    for (int l4=0; l4<4; l4++){
      uint4 uu = u4[l4];
      acc[0][l4*4+0] = dot2u(uu.x, w0, acc[0][l4*4+0]);
      acc[0][l4*4+1] = dot2u(uu.y, w0, acc[0][l4*4+1]);
      acc[0][l4*4+2] = dot2u(uu.z, w0, acc[0][l4*4+2]);
      acc[0][l4*4+3] = dot2u(uu.w, w0, acc[0][l4*4+3]);
      acc[1][l4*4+0] = dot2u(uu.x, w1, acc[1][l4*4+0]);
      acc[1][l4*4+1] = dot2u(uu.y, w1, acc[1][l4*4+1]);
      acc[1][l4*4+2] = dot2u(uu.z, w1, acc[1][l4*4+2]);
      acc[1][l4*4+3] = dot2u(uu.w, w1, acc[1][l4*4+3]);
      acc[2][l4*4+0] = dot2u(uu.x, w2, acc[2][l4*4+0]);
      acc[2][l4*4+1] = dot2u(uu.y, w2, acc[2][l4*4+1]);
      acc[2][l4*4+2] = dot2u(uu.z, w2, acc[2][l4*4+2]);
      acc[2][l4*4+3] = dot2u(uu.w, w2, acc[2][l4*4+3]);
    }
  }
  #pragma unroll
  for (int l=0;l<16;l++){
    int li = l0 + l;
    if (li < L2){
      _Float16* pr = pre + ((size_t)n*L2 + li)*768;
      pr[t]       = (_Float16)acc[0][l];
      pr[t+256]   = (_Float16)acc[1][l];
      pr[t+512]   = (_Float16)acc[2][l];
    }
  }
}

// ---------------- biLSTM scan v3: recurrent-only, 512 thr (K-split x2), G=4 seqs ----------
__global__ __launch_bounds__(512) void k_lstm3(
    const _Float16* __restrict__ pre, _Float16* __restrict__ r,
    const unsigned int* __restrict__ wh_f, const unsigned int* __restrict__ wh_b,
    int N, int L2){
  __shared__ unsigned int hh2[384];      // [d2][s] packed h pairs
  __shared__ float gshp[2*4*768];        // [half][s][gate]
  _Float16* hh2h = (_Float16*)hh2;

  int t = threadIdx.x;
  int half = t >> 8;
  int tt = t & 255;
  int dir = blockIdx.y;
  int n0 = blockIdx.x*4;
  const unsigned int* wh = (dir ? wh_b : wh_f) + (size_t)half*48*768;
  const _Float16* prd = pre + (size_t)dir*(size_t)N*L2*768;
  float cst[2] = {0.f,0.f};
  for (int idx=t; idx<384; idx+=512) hh2[idx]=0u;
  __syncthreads();

  for (int step=0; step<L2; step++){
    int l = dir ? (L2-1-step) : step;
    float a0_0=0.f,a0_1=0.f,a0_2=0.f,a0_3=0.f;
    float a1_0=0.f,a1_1=0.f,a1_2=0.f,a1_3=0.f;
    float a2_0=0.f,a2_1=0.f,a2_2=0.f,a2_3=0.f;
    if (half==0){
      #pragma unroll
      for (int s=0;s<4;s++){
        if (n0+s < N){
          const _Float16* pp = prd + ((size_t)(n0+s)*L2 + l)*768;
          float v0 = (float)pp[tt], v1 = (float)pp[tt+256], v2 = (float)pp[tt+512];
          if (s==0){ a0_0=v0; a1_0=v1; a2_0=v2; }
          else if (s==1){ a0_1=v0; a1_1=v1; a2_1=v2; }
          else if (s==2){ a0_2=v0; a1_2=v1; a2_2=v2; }
          else { a0_3=v0; a1_3=v1; a2_3=v2; }
        }
      }
    }
    const uint4* hv = ((const uint4*)hh2) + half*48;
    #pragma unroll 4
    for (int d2=0; d2<48; d2++){
      uint4 hh = hv[d2];
      unsigned int w0 = wh[(size_t)d2*768 + tt];
      unsigned int w1 = wh[(size_t)d2*768 + tt + 256];
      unsigned int w2 = wh[(size_t)d2*768 + tt + 512];
      a0_0 = dot2u(hh.x, w0, a0_0);
      a0_1 = dot2u(hh.y, w0, a0_1);
      a0_2 = dot2u(hh.z, w0, a0_2);
      a0_3 = dot2u(hh.w, w0, a0_3);
      a1_0 = dot2u(hh.x, w1, a1_0);
      a1_1 = dot2u(hh.y, w1, a1_1);
      a1_2 = dot2u(hh.z, w1, a1_2);
      a1_3 = dot2u(hh.w, w1, a1_3);
      a2_0 = dot2u(hh.x, w2, a2_0);
      a2_1 = dot2u(hh.y, w2, a2_1);
      a2_2 = dot2u(hh.z, w2, a2_2);
      a2_3 = dot2u(hh.w, w2, a2_3);
    }
    float* gp = gshp + half*3072;
    gp[0*768 + tt]       = a0_0; gp[1*768 + tt]       = a0_1; gp[2*768 + tt]       = a0_2; gp[3*768 + tt]       = a0_3;
    gp[0*768 + 256 + tt] = a1_0; gp[1*768 + 256 + tt] = a1_1; gp[2*768 + 256 + tt] = a1_2; gp[3*768 + 256 + tt] = a1_3;
    gp[0*768 + 512 + tt] = a2_0; gp[1*768 + 512 + tt] = a2_1; gp[2*768 + 512 + tt] = a2_2; gp[3*768 + 512 + tt] = a2_3;
    __syncthreads();

    #pragma unroll
    for (int q=0; q<2; q++){
      int idx = t + q*512;
      if (idx < 768){
        int s = idx/192, j = idx - s*192;
        float ig = sigf(  gshp[s*768 + j]       + gshp[3072 + s*768 + j]);
        float fg = sigf(  gshp[s*768 + 192 + j] + gshp[3072 + s*768 + 192 + j]);
        float gg = tanhf_(gshp[s*768 + 384 + j] + gshp[3072 + s*768 + 384 + j]);
        float og = sigf(  gshp[s*768 + 576 + j] + gshp[3072 + s*768 + 576 + j]);
        cst[q] = fg*cst[q] + ig*gg;
        float hn = og*tanhf_(cst[q]);
        if (n0+s < N) r[((size_t)(n0+s)*L2 + l)*384 + dir*192 + j] = (_Float16)hn;
        hh2h[(j>>1)*8 + s*2 + (j&1)] = (_Float16)hn;
      }
    }
    __syncthreads();
  }
}

// ---------------- conv_transpose1d v2 (f16 r input) ----------
__global__ __launch_bounds__(256) void k_convt2(
    const _Float16* __restrict__ r, const float* __restrict__ wt2,
    const float* __restrict__ bias, const float* __restrict__ resid,
    float* __restrict__ dst, int L2, int OL, int mode){
  __shared__ float wsh[384*48];
  int n = blockIdx.y;
  int p0 = blockIdx.x*64;
  int tid = threadIdx.x;
  int pos = p0 + (tid >> 2);
  int cq = tid & 3;
  float4 acc[3];
  acc[0] = make_float4(0,0,0,0); acc[1] = make_float4(0,0,0,0); acc[2] = make_float4(0,0,0,0);

  for (int k=0; k<4; k++){
    const float4* wk4 = (const float4*)(wt2 + (size_t)k*384*48);
    float4* wsh4 = (float4*)wsh;
    for (int i=tid; i<4608; i+=256) wsh4[i] = wk4[i];
    __syncthreads();
    int l = pos - k;
    if (l >= 0 && l < L2){
      const uint2* rr2 = (const uint2*)(r + ((size_t)n*L2 + l)*384);
      const float4* wb = (const float4*)(wsh + cq*12);
      #pragma unroll 4
      for (int ii4=0; ii4<96; ii4++){
        uint2 rp = rr2[ii4];
        v2h p0h = __builtin_bit_cast(v2h, rp.x);
        v2h p1h = __builtin_bit_cast(v2h, rp.y);
        float4 rv = make_float4((float)p0h.x, (float)p0h.y, (float)p1h.x, (float)p1h.y);
        const float4* w0 = wb + (ii4*4)*12;
        float4 wa, wbv, wc;
        wa = w0[0]; wbv = w0[1]; wc = w0[2];
        acc[0].x += rv.x*wa.x; acc[0].y += rv.x*wa.y; acc[0].z += rv.x*wa.z; acc[0].w += rv.x*wa.w;
        acc[1].x += rv.x*wbv.x; acc[1].y += rv.x*wbv.y; acc[1].z += rv.x*wbv.z; acc[1].w += rv.x*wbv.w;
        acc[2].x += rv.x*wc.x; acc[2].y += rv.x*wc.y; acc[2].z += rv.x*wc.z; acc[2].w += rv.x*wc.w;
        wa = w0[12]; wbv = w0[13]; wc = w0[14];
        acc[0].x += rv.y*wa.x; acc[0].y += rv.y*wa.y; acc[0].z += rv.y*wa.z; acc[0].w += rv.y*wa.w;
        acc[1].x += rv.y*wbv.x; acc[1].y += rv.y*wbv.y; acc[1].z += rv.y*wbv.z; acc[1].w += rv.y*wbv.w;
        acc[2].x += rv.y*wc.x; acc[2].y += rv.y*wc.y; acc[2].z += rv.y*wc.z; acc[2].w += rv.y*wc.w;
        wa = w0[24]; wbv = w0[25]; wc = w0[26];
        acc[0].x += rv.z*wa.x; acc[0].y += rv.z*wa.y; acc[0].z += rv.z*wa.z; acc[0].w += rv.z*wa.w;
        acc[1].x += rv.z*wbv.x; acc[1].y += rv.z*wbv.y; acc[1].z += rv.z*wbv.z; acc[1].w += rv.z*wbv.w;
        acc[2].x += rv.z*wc.x; acc[2].y += rv.z*wc.y; acc[2].z += rv.z*wc.z; acc[2].w += rv.z*wc.w;
        wa = w0[36]; wbv = w0[37]; wc = w0[38];
        acc[0].x += rv.w*wa.x; acc[0].y += rv.w*wa.y; acc[0].z += rv.w*wa.z; acc[0].w += rv.w*wa.w;
        acc[1].x += rv.w*wbv.x; acc[1].y += rv.w*wbv.y; acc[1].z += rv.w*wbv.z; acc[1].w += rv.w*wbv.w;
        acc[2].x += rv.w*wc.x; acc[2].y += rv.w*wc.y; acc[2].z += rv.w*wc.z; acc[2].w += rv.w*wc.w;
      }
    }
    __syncthreads();
  }

  if (pos < OL){
    float a[12];
    a[0]=acc[0].x; a[1]=acc[0].y; a[2]=acc[0].z; a[3]=acc[0].w;
    a[4]=acc[1].x; a[5]=acc[1].y; a[6]=acc[1].z; a[7]=acc[1].w;
    a[8]=acc[2].x; a[9]=acc[2].y; a[10]=acc[2].z; a[11]=acc[2].w;
    for (int c12=0; c12<12; c12++){
      int c = cq*12 + c12;
      size_t oidx;
      if (mode==0){ int b = n/250, t = n%250; oidx = (((size_t)b*48+c)*250+t)*65 + pos; }
      else        { int b = n/65,  q = n%65;  oidx = (((size_t)b*48+c)*250+pos)*65 + q; }
      dst[oidx] = a[c12] + bias[c] + resid[oidx];
    }
  }
}

// ---------------- head projection + per-head leaky ----------------
__global__ void k_headproj(const float* __restrict__ bt, const float* __restrict__ w,
                           const float* __restrict__ bias, const float* __restrict__ alpha,
                           float* __restrict__ dst, int dim){
  int i = blockIdx.x*blockDim.x + threadIdx.x;
  int total = 4*2*250*dim*65;
  if (i >= total) return;
  int f = i % 65;
  int e = (i/65) % dim;
  int t = (i/(65*dim)) % 250;
  int b = (i/(65*dim*250)) % 2;
  int h = i/(65*dim*250*2);
  const float* wr = w + (h*dim+e)*48;
  const float* bp = bt + (size_t)b*48*250*65 + (size_t)t*65 + f;
  float acc = bias[h*dim+e];
  for (int c=0;c<48;c++) acc += bp[(size_t)c*250*65]*wr[c];
  if (acc < 0.f) acc *= alpha[h];
  dst[i] = acc;
}

// ---------------- ln_clamp over (e,f) per (h,b,t) block, in place ----------------
__global__ void k_headln(float* __restrict__ buf, const float* __restrict__ g,
                         const float* __restrict__ bt_, int dim){
  __shared__ float r1[256];
  __shared__ float r2[256];
  int bx = blockIdx.x;
  int h = bx/500;
  int n = dim*65;
  float* p = buf + (size_t)bx*n;
  const float* gp = g + h*n;
  const float* bp = bt_ + h*n;
  float s=0.f, ss=0.f;
  for (int k=threadIdx.x; k<n; k+=256){ float v=p[k]; s+=v; ss+=v*v; }
  r1[threadIdx.x]=s; r2[threadIdx.x]=ss; __syncthreads();
  for (int st=128; st>0; st>>=1){
    if (threadIdx.x < st){ r1[threadIdx.x]+=r1[threadIdx.x+st]; r2[threadIdx.x]+=r2[threadIdx.x+st]; }
    __syncthreads();
  }
  float mu = r1[0]/(float)n, var = r2[0]/(float)n - mu*mu;
  float rs = rsqrtf(fmaxf(var, EPSV));
  for (int k=threadIdx.x; k<n; k+=256) p[k] = (p[k]-mu)*rs*gp[k] + bp[k];
}

// ---------------- flattened-head attention: block per (h,b,t) ----------------
__global__ void k_headattn(const float* __restrict__ Qp, const float* __restrict__ Kp,
                           const float* __restrict__ Vp, float* __restrict__ Vo){
  __shared__ float qsh[520];
  __shared__ float psh[250];
  __shared__ float r1[256];
  int bx = blockIdx.x;
  int t = bx % 250;
  int b = (bx/250) % 2;
  int h = bx/500;
  int hb = h*2 + b;
  const float* qrow = Qp + ((size_t)hb*250 + t)*520;
  for (int d=threadIdx.x; d<520; d+=256) qsh[d] = qrow[d];
  __syncthreads();
  const float scale = rsqrtf(520.0f);
  float lmax = -1e30f;
  for (int s2=threadIdx.x; s2<250; s2+=256){
    const float* kr = Kp + ((size_t)hb*250 + s2)*520;
    float acc = 0.f;
    for (int d=0; d<520; d++) acc += qsh[d]*kr[d];
    acc *= scale;
    psh[s2] = acc;
    lmax = fmaxf(lmax, acc);
  }
  r1[threadIdx.x] = lmax; __syncthreads();
  for (int st=128; st>0; st>>=1){
    if (threadIdx.x<st) r1[threadIdx.x]=fmaxf(r1[threadIdx.x], r1[threadIdx.x+st]);
    __syncthreads();
  }
  float m = r1[0];
  __syncthreads();
  float lsum = 0.f;
  for (int s2=threadIdx.x; s2<250; s2+=256){
    float e = __expf(psh[s2]-m);
    psh[s2] = e;
    lsum += e;
  }
  r1[threadIdx.x]=lsum; __syncthreads();
  for (int st=128; st>0; st>>=1){
    if (threadIdx.x<st) r1[threadIdx.x]+=r1[threadIdx.x+st];
    __syncthreads();
  }
  float inv = 1.0f/r1[0];
  for (int d=threadIdx.x; d<780; d+=256){
    float acc = 0.f;
    const float* vcol = Vp + (size_t)hb*250*780 + d;
    for (int s2=0; s2<250; s2++) acc += psh[s2]*vcol[(size_t)s2*780];
    acc *= inv;
    int e = d/65, f = d%65;
    Vo[(((size_t)b*48 + h*12 + e)*250 + t)*65 + f] = acc;
  }
}

// ---------------- p-projection + leaky ----------------
__global__ void k_pproj(const float* __restrict__ Vo, const float* __restrict__ pw,
                        const float* __restrict__ pb, const float* __restrict__ pa,
                        float* __restrict__ pj){
  int i = blockIdx.x*blockDim.x + threadIdx.x;
  if (i >= 2*48*250*65) return;
  int f = i % 65;
  int t = (i/65) % 250;
  int o = (i/(65*250)) % 48;
  int b = i/(65*250*48);
  const float* vp = Vo + (size_t)b*48*250*65 + (size_t)t*65 + f;
  const float* wr = pw + o*48;
  float acc = pb[o];
  for (int c=0;c<48;c++) acc += vp[(size_t)c*250*65]*wr[c];
  if (acc < 0.f) acc *= pa[0];
  pj[i] = acc;
}

// ---------------- ln_clamp over (c,f) per (b,t) + residual ----------------
__global__ void k_pln(const float* __restrict__ pj, const float* __restrict__ pg,
                      const float* __restrict__ pbt, const float* __restrict__ inter,
                      float* __restrict__ outb){
  __shared__ float r1[256];
  __shared__ float r2[256];
  int bx = blockIdx.x;
  int t = bx % 250, b = bx/250;
  const float* base = pj + (size_t)b*48*250*65 + (size_t)t*65;
  float s=0.f, ss=0.f;
  for (int k=threadIdx.x; k<3120; k+=256){
    int c = k/65, f = k%65;
    float v = base[(size_t)c*250*65 + f];
    s+=v; ss+=v*v;
  }
  r1[threadIdx.x]=s; r2[threadIdx.x]=ss; __syncthreads();
  for (int st=128; st>0; st>>=1){
    if (threadIdx.x<st){ r1[threadIdx.x]+=r1[threadIdx.x+st]; r2[threadIdx.x]+=r2[threadIdx.x+st]; }
    __syncthreads();
  }
  float mu = r1[0]*(1.0f/3120.0f), var = r2[0]*(1.0f/3120.0f) - mu*mu;
  float rs = rsqrtf(fmaxf(var, EPSV));
  for (int k=threadIdx.x; k<3120; k+=256){
    int c = k/65, f = k%65;
    size_t idx = (((size_t)b*48+c)*250 + t)*65 + f;
    float v = pj[idx];
    outb[idx] = (v-mu)*rs*pg[c*65+f] + pbt[c*65+f] + inter[idx];
  }
}

// ---------------- fin 1x1: (B,48,...) -> (B,384,...) ----------------
__global__ void k_fin(const float* __restrict__ outb, const float* __restrict__ w,
                      const float* __restrict__ bias, float* __restrict__ pi){
  int i = blockIdx.x*blockDim.x + threadIdx.x;
  if (i >= 2*384*250*65) return;
  int f = i % 65;
  int t = (i/65) % 250;
  int o = (i/(65*250)) % 384;
  int b = i/(65*250*384);
  const float* xp = outb + (size_t)b*48*250*65 + (size_t)t*65 + f;
  const float* wr = w + o*48;
  float acc = bias[o];
  for (int c=0;c<48;c++) acc += xp[(size_t)c*250*65]*wr[c];
  pi[i] = acc;
}

// ---------------- depthwise 3x3 both halves + gelu-gate ----------------
__global__ void k_dwg(const float* __restrict__ pi, const float* __restrict__ dw,
                      const float* __restrict__ db, float* __restrict__ gbuf){
  int i = blockIdx.x*blockDim.x + threadIdx.x;
  if (i >= 2*192*250*65) return;
  int f = i % 65;
  int t = (i/65) % 250;
  int j = (i/(65*250)) % 192;
  int b = i/(65*250*192);
  float x12[2];
  for (int half=0; half<2; half++){
    int ch = j + half*192;
    const float* base = pi + ((size_t)b*384 + ch)*250*65;
    const float* wr = dw + ch*9;
    float acc = db[ch];
    for (int dt=-1; dt<=1; dt++){
      int tt = t+dt;
      if (tt<0||tt>=250) continue;
      for (int df=-1; df<=1; df++){
        int ff = f+df;
        if (ff<0||ff>=65) continue;
        acc += base[(size_t)tt*65+ff]*wr[(dt+1)*3 + (df+1)];
      }
    }
    x12[half]=acc;
  }
  float x1 = x12[0];
  float g = 0.5f*x1*(1.0f+erff(x1*0.70710678118654752f));
  gbuf[i] = g * x12[1];
}

// ---------------- final 1x1 (192->48) + residual -> d_out ----------------
__global__ void k_final(const float* __restrict__ gbuf, const float* __restrict__ w,
                        const float* __restrict__ bias, const float* __restrict__ outb,
                        float* __restrict__ dout){
  int i = blockIdx.x*blockDim.x + threadIdx.x;
  if (i >= 2*48*250*65) return;
  int f = i % 65;
  int t = (i/65) % 250;
  int o = (i/(65*250)) % 48;
  int b = i/(65*250*48);
  const float* gp = gbuf + (size_t)b*192*250*65 + (size_t)t*65 + f;
  const float* wr = w + o*192;
  float acc = bias[o];
  for (int j=0;j<192;j++) acc += gp[(size_t)j*250*65]*wr[j];
  dout[i] = acc + outb[i];
}

extern "C" void kernel_launch(void* const* d_in, const int* in_sizes, int n_in,
                              void* d_out, int out_size, void* d_ws, size_t ws_size,
                              hipStream_t stream) {
  (void)in_sizes; (void)n_in; (void)out_size; (void)ws_size;
  auto in = [&](int i){ return (const float*)d_in[i]; };
  const float* x        = in(0);
  const float* af_in_w  = in(1);  const float* af_in_b  = in(2);
  const float* af_out_w = in(3);  const float* af_out_b = in(4);
  const float* at_in_w  = in(5);  const float* at_in_b  = in(6);
  const float* at_out_w = in(7);  const float* at_out_b = in(8);
  const float* naf_g = in(9),  *naf_b = in(10), *nat_g = in(11), *nat_b = in(12);
  const float* intra_ng = in(13), *intra_nb = in(14), *inter_ng = in(15), *inter_nb = in(16);
  const float* intra_wif = in(17), *intra_whf = in(18), *intra_bif = in(19), *intra_bhf = in(20);
  const float* intra_wib = in(21), *intra_whb = in(22), *intra_bib = in(23), *intra_bhb = in(24);
  const float* inter_wif = in(25), *inter_whf = in(26), *inter_bif = in(27), *inter_bhf = in(28);
  const float* inter_wib = in(29), *inter_whb = in(30), *inter_bib = in(31), *inter_bhb = in(32);
  const float* il_w = in(33), *il_b = in(34), *itl_w = in(35), *itl_b = in(36);
  const float* qw = in(37), *qb = in(38), *qa = in(39), *qg = in(40), *qbt = in(41);
  const float* kw = in(42), *kb = in(43), *ka = in(44), *kg = in(45), *kbt = in(46);
  const float* vw = in(47), *vb = in(48), *va = in(49), *vg = in(50), *vbt = in(51);
  const float* pw = in(52), *pb = in(53), *pa = in(54), *pg = in(55), *pbt = in(56);
  const float* fin_w = in(57), *fin_b = in(58), *fdw_w = in(59), *fdw_b = in(60);
  const float* fout_w = in(61), *fout_b = in(62);

  float* ws = (float*)d_ws;
  float* buf_intra = ws + 0;                        // 1,560,000
  float* buf_bt    = ws + 1560000;                  // 1,560,000
  float* buf_out   = ws + 3120000;                  // 1,560,000
  unsigned int* wpk = (unsigned int*)(ws + 4680000);// 8 * 73,728 words
  float* wtc       = ws + 5269824;                  // 2 * 73,728 words
  float* scr       = ws + 5417280;                  // arena
  // staging (dead before pre-gates)
  float* s_seq2 = scr;                              // 1,560,000
  float* s_seq  = scr + 1560000;                    // 1,560,000
  float* s_qkv  = scr + 3120000;                    // 4,680,000
  float* s_att  = scr + 7800000;                    // 1,560,000
  // lstm buffers
  _Float16* s_pre = (_Float16*)(scr + 1560000);     // up to 49,320,960 halfs (2 dirs)
  _Float16* s_r   = (_Float16*)(scr + 26220480);    // up to 12,330,240 halfs
  // phase3 aliases
  float* s_Qh = scr;
  float* s_Kh = scr + 1040000;
  float* s_Vh = scr + 2080000;
  float* s_Vo = scr + 3640000;
  float* s_pj = scr + 5200000;
  // phase4 aliases
  float* s_pi = scr;
  float* s_g  = scr + 12480000;

  const int thr = 256;
  auto cdiv = [](int a, int b){ return (a+b-1)/b; };

  // ---------------- weight prep ----------------
  k_wpack<<<cdiv(73728,thr),thr,0,stream>>>(intra_wif, wpk + 0*73728);
  k_wpack<<<cdiv(73728,thr),thr,0,stream>>>(intra_whf, wpk + 1*73728);
  k_wpack<<<cdiv(73728,thr),thr,0,stream>>>(intra_wib, wpk + 2*73728);
  k_wpack<<<cdiv(73728,thr),thr,0,stream>>>(intra_whb, wpk + 3*73728);
  k_wpack<<<cdiv(73728,thr),thr,0,stream>>>(inter_wif, wpk + 4*73728);
  k_wpack<<<cdiv(73728,thr),thr,0,stream>>>(inter_whf, wpk + 5*73728);
  k_wpack<<<cdiv(73728,thr),thr,0,stream>>>(inter_wib, wpk + 6*73728);
  k_wpack<<<cdiv(73728,thr),thr,0,stream>>>(inter_whb, wpk + 7*73728);
  k_wtc<<<cdiv(73728,thr),thr,0,stream>>>(il_w,  wtc + 0*73728);
  k_wtc<<<cdiv(73728,thr),thr,0,stream>>>(itl_w, wtc + 1*73728);

  // ---------------- Phase 1: intra (along Q): N=500, L2=62, SL=65 ----------------
  k_ln_chan<<<cdiv(2*250*65,thr), thr, 0, stream>>>(x, s_seq, intra_ng, intra_nb, 0);
  k_qkv<<<cdiv(500*65*144,thr), thr, 0, stream>>>(s_seq, af_in_w, af_in_b, s_qkv, 500*65);
  k_mha<<<dim3(500,4), 256, 0, stream>>>(s_qkv, s_att, 500, 65);
  k_projres<<<cdiv(500*65*48,thr), thr, 0, stream>>>(s_att, s_seq, af_out_w, af_out_b, s_seq2, 500*65);
  k_rowln<<<cdiv(32500,thr), thr, 0, stream>>>(s_seq2, naf_g, naf_b, 32500);
  {
    const size_t dstr = (size_t)500*62*768;
    k_pregates<<<dim3(4,500), 256, 0, stream>>>(s_seq2, wpk+0*73728, intra_bif, intra_bhf, s_pre,        62, 65);
    k_pregates<<<dim3(4,500), 256, 0, stream>>>(s_seq2, wpk+2*73728, intra_bib, intra_bhb, s_pre + dstr, 62, 65);
  }
  k_lstm3<<<dim3(125,2), 512, 0, stream>>>(s_pre, s_r, wpk+1*73728, wpk+3*73728, 500, 62);
  k_convt2<<<dim3(2,500), 256, 0, stream>>>(s_r, wtc+0*73728, il_b, x, buf_intra, 62, 65, 0);

  // ---------------- Phase 2: inter (along T): N=130, L2=247, SL=250 ----------------
  k_ln_chan<<<cdiv(2*250*65,thr),thr,0,stream>>>(buf_intra, s_seq, inter_ng, inter_nb, 1);
  k_qkv<<<cdiv(130*250*144,thr),thr,0,stream>>>(s_seq, at_in_w, at_in_b, s_qkv, 130*250);
  k_mha<<<dim3(130,4), 256, 0, stream>>>(s_qkv, s_att, 130, 250);
  k_projres<<<cdiv(130*250*48,thr),thr,0,stream>>>(s_att, s_seq, at_out_w, at_out_b, s_seq2, 130*250);
  k_rowln<<<cdiv(32500,thr),thr,0,stream>>>(s_seq2, nat_g, nat_b, 32500);
  {
    const size_t dstr = (size_t)130*247*768;
    k_pregates<<<dim3(16,130), 256, 0, stream>>>(s_seq2, wpk+4*73728, inter_bif, inter_bhf, s_pre,        247, 250);
    k_pregates<<<dim3(16,130), 256, 0, stream>>>(s_seq2, wpk+6*73728, inter_bib, inter_bhb, s_pre + dstr, 247, 250);
  }
  k_lstm3<<<dim3(33,2), 512, 0, stream>>>(s_pre, s_r, wpk+5*73728, wpk+7*73728, 130, 247);
  k_convt2<<<dim3(4,130), 256, 0, stream>>>(s_r, wtc+1*73728, itl_b, buf_intra, buf_bt, 247, 250, 1);

  // ---------------- Phase 3: flattened-head attention ----------------
  k_headproj<<<cdiv(4*2*250*8*65,thr),thr,0,stream>>>(buf_bt, qw, qb, qa, s_Qh, 8);
  k_headln<<<2000,256,0,stream>>>(s_Qh, qg, qbt, 8);
  k_headproj<<<cdiv(4*2*250*8*65,thr),thr,0,stream>>>(buf_bt, kw, kb, ka, s_Kh, 8);
  k_headln<<<2000,256,0,stream>>>(s_Kh, kg, kbt, 8);
  k_headproj<<<cdiv(4*2*250*12*65,thr),thr,0,stream>>>(buf_bt, vw, vb, va, s_Vh, 12);
  k_headln<<<2000,256,0,stream>>>(s_Vh, vg, vbt, 12);
  k_headattn<<<2000,256,0,stream>>>(s_Qh, s_Kh, s_Vh, s_Vo);
  k_pproj<<<cdiv(2*48*250*65,thr),thr,0,stream>>>(s_Vo, pw, pb, pa, s_pj);
  k_pln<<<500,256,0,stream>>>(s_pj, pg, pbt, buf_bt, buf_out);

  // ---------------- Phase 4: FFN ----------------
  k_fin<<<cdiv(2*384*250*65,thr),thr,0,stream>>>(buf_out, fin_w, fin_b, s_pi);
  k_dwg<<<cdiv(2*192*250*65,thr),thr,0,stream>>>(s_pi, fdw_w, fdw_b, s_g);
  k_final<<<cdiv(2*48*250*65,thr),thr,0,stream>>>(s_g, fout_w, fout_b, buf_out, (float*)d_out);
}

// Round 4
// 2813.433 us; speedup vs baseline: 5.4045x; 1.2157x over previous
//
#include <hip/hip_runtime.h>
#include <math.h>

#define EPSV 1e-5f

typedef _Float16 v2h __attribute__((ext_vector_type(2)));

__device__ __forceinline__ float sigf(float x){ return 1.0f/(1.0f+__expf(-x)); }
__device__ __forceinline__ float tanhf_(float x){
  float c = fminf(fmaxf(x,-10.f),10.f);
  float e = __expf(2.0f*c);
  return (e-1.0f)/(e+1.0f);
}

__device__ __forceinline__ float dot2u(unsigned int a, unsigned int b, float c){
#if __has_builtin(__builtin_amdgcn_fdot2)
  v2h av = __builtin_bit_cast(v2h, a);
  v2h bv = __builtin_bit_cast(v2h, b);
  return __builtin_amdgcn_fdot2(av, bv, c, false);
#else
  v2h av = __builtin_bit_cast(v2h, a);
  v2h bv = __builtin_bit_cast(v2h, b);
  return c + (float)av.x*(float)bv.x + (float)av.y*(float)bv.y;
#endif
}

// ---------------- LN over channel dim -> channel-last seq ----------------
__global__ void k_ln_chan(const float* __restrict__ src, float* __restrict__ dst,
                          const float* __restrict__ g, const float* __restrict__ bb, int mode){
  int i = blockIdx.x*blockDim.x + threadIdx.x;
  const int total = 2*250*65;
  if (i >= total) return;
  int q = i % 65; int t = (i/65) % 250; int b = i/(65*250);
  const float* p = src + (size_t)b*48*250*65 + (size_t)t*65 + q;
  float s=0.f, ss=0.f;
  for (int c=0;c<48;c++){ float v = p[(size_t)c*250*65]; s+=v; ss+=v*v; }
  float mu = s*(1.0f/48.0f);
  float var = ss*(1.0f/48.0f) - mu*mu;
  float rs = rsqrtf(fmaxf(var, EPSV));
  float* d = (mode==0) ? dst + ((size_t)(b*250+t)*65 + q)*48
                       : dst + ((size_t)(b*65+q)*250 + t)*48;
  for (int c=0;c<48;c++){ float v = p[(size_t)c*250*65]; d[c] = (v-mu)*rs*g[c] + bb[c]; }
}

// ---------------- qkv = seq @ in_w.T + in_b ----------------
__global__ void k_qkv(const float* __restrict__ seq, const float* __restrict__ w,
                      const float* __restrict__ bias, float* __restrict__ qkv, int NL){
  int i = blockIdx.x*blockDim.x + threadIdx.x;
  if (i >= NL*144) return;
  int j = i % 144; int nl = i / 144;
  const float* srow = seq + (size_t)nl*48;
  const float* wrow = w + j*48;
  float acc = bias[j];
  for (int c=0;c<48;c++) acc += srow[c]*wrow[c];
  qkv[i] = acc;
}

// ---------------- MHA core ----------------
__global__ void k_mha(const float* __restrict__ qkv, float* __restrict__ att, int N, int L){
  __shared__ float shq[250*12];
  __shared__ float shk[250*12];
  __shared__ float shv[250*12];
  int n = blockIdx.x, h = blockIdx.y;
  const float* base = qkv + (size_t)n*L*144 + h*12;
  for (int i = threadIdx.x; i < L*12; i += blockDim.x){
    int l = i/12, d = i%12;
    shq[i] = base[(size_t)l*144 + d];
    shk[i] = base[(size_t)l*144 + 48 + d];
    shv[i] = base[(size_t)l*144 + 96 + d];
  }
  __syncthreads();
  const float scale = 0.28867513459481287f;
  for (int r = threadIdx.x; r < L; r += blockDim.x){
    float m = -1e30f, den = 0.0f, o[12];
    for (int d=0; d<12; d++) o[d]=0.0f;
    const float* qr = shq + r*12;
    for (int j=0; j<L; j++){
      const float* kr = shk + j*12;
      float s = 0.f;
      for (int d=0; d<12; d++) s += qr[d]*kr[d];
      s *= scale;
      if (s > m){
        float corr = __expf(m - s);
        den *= corr;
        for (int d=0; d<12; d++) o[d] *= corr;
        m = s;
      }
      float e = __expf(s - m);
      den += e;
      const float* vr = shv + j*12;
      for (int d=0; d<12; d++) o[d] += e*vr[d];
    }
    float inv = 1.0f/den;
    float* outp = att + ((size_t)n*L + r)*48 + h*12;
    for (int d=0; d<12; d++) outp[d] = o[d]*inv;
  }
}

// ---------------- out proj + residual ----------------
__global__ void k_projres(const float* __restrict__ att, const float* __restrict__ seq,
                          const float* __restrict__ w, const float* __restrict__ bias,
                          float* __restrict__ dst, int NL){
  int i = blockIdx.x*blockDim.x + threadIdx.x;
  if (i >= NL*48) return;
  int o = i % 48; int nl = i/48;
  const float* ar = att + (size_t)nl*48;
  const float* wr = w + o*48;
  float acc = bias[o] + seq[i];
  for (int c=0;c<48;c++) acc += ar[c]*wr[c];
  dst[i] = acc;
}

// ---------------- torch_ln over last dim (48), in place ----------------
__global__ void k_rowln(float* __restrict__ buf, const float* __restrict__ g,
                        const float* __restrict__ bb, int NL){
  int nl = blockIdx.x*blockDim.x + threadIdx.x;
  if (nl >= NL) return;
  float* p = buf + (size_t)nl*48;
  float s=0.f, ss=0.f;
  for (int c=0;c<48;c++){ float v=p[c]; s+=v; ss+=v*v; }
  float mu = s*(1.0f/48.0f);
  float var = ss*(1.0f/48.0f) - mu*mu;
  float rs = rsqrtf(var + EPSV);
  for (int c=0;c<48;c++) p[c] = (p[c]-mu)*rs*g[c] + bb[c];
}

// ---------------- pack LSTM weight fp32 [768][192] -> half2-uint [96][768] ----------------
__global__ void k_wpack(const float* __restrict__ w, unsigned int* __restrict__ wp){
  int i = blockIdx.x*blockDim.x + threadIdx.x;
  if (i >= 96*768) return;
  int g = i % 768, d2 = i / 768;
  v2h v; v.x = (_Float16)w[g*192 + 2*d2]; v.y = (_Float16)w[g*192 + 2*d2 + 1];
  wp[(size_t)d2*768 + g] = __builtin_bit_cast(unsigned int, v);
}

// ---------------- transpose convT weight [384][48][4] -> [k][ii][c] ----------------
__global__ void k_wtc(const float* __restrict__ w, float* __restrict__ wt){
  int i = blockIdx.x*blockDim.x + threadIdx.x;
  if (i >= 4*384*48) return;
  int c = i % 48; int ii = (i/48) % 384; int k = i/(48*384);
  wt[i] = w[ii*192 + c*4 + k];
}

// ---------------- pre-gates GEMM: pre[n][l][g] = u.wi^T + bi + bh (f16 out) ----------------
__global__ __launch_bounds__(256) void k_pregates(
    const float* __restrict__ seq2, const unsigned int* __restrict__ wi,
    const float* __restrict__ bi, const float* __restrict__ bh,
    _Float16* __restrict__ pre, int L2, int SL){
  __shared__ unsigned int ut[96*16];
  int n = blockIdx.y;
  int l0 = blockIdx.x*16;
  int t = threadIdx.x;
  for (int idx=t; idx<1536; idx+=256){
    int l = idx & 15, d2 = idx >> 4;
    int li = l0 + l;
    int c = d2 >> 1, k0 = (d2 & 1)*2;
    float u0=0.f, u1=0.f;
    if (li < L2){
      const float* p = seq2 + ((size_t)n*SL + li)*48;
      u0 = p[k0*48 + c];
      u1 = p[(k0+1)*48 + c];
    }
    v2h v; v.x=(_Float16)u0; v.y=(_Float16)u1;
    ut[d2*16 + l] = __builtin_bit_cast(unsigned int, v);
  }
  __syncthreads();
  float acc[3][16];
  float b0 = bi[t] + bh[t];
  float b1 = bi[t+256] + bh[t+256];
  float b2 = bi[t+512] + bh[t+512];
  #pragma unroll
  for (int l=0;l<16;l++){ acc[0][l]=b0; acc[1][l]=b1; acc[2][l]=b2; }
  #pragma unroll 4
  for (int d2=0; d2<96; d2++){
    unsigned int w0 = wi[(size_t)d2*768 + t];
    unsigned int w1 = wi[(size_t)d2*768 + t + 256];
    unsigned int w2 = wi[(size_t)d2*768 + t + 512];
    const uint4* u4 = (const uint4*)(ut + d2*16);
    #pragma unroll
    for (int l4=0; l4<4; l4++){
      uint4 uu = u4[l4];
      acc[0][l4*4+0] = dot2u(uu.x, w0, acc[0][l4*4+0]);
      acc[0][l4*4+1] = dot2u(uu.y, w0, acc[0][l4*4+1]);
      acc[0][l4*4+2] = dot2u(uu.z, w0, acc[0][l4*4+2]);
      acc[0][l4*4+3] = dot2u(uu.w, w0, acc[0][l4*4+3]);
      acc[1][l4*4+0] = dot2u(uu.x, w1, acc[1][l4*4+0]);
      acc[1][l4*4+1] = dot2u(uu.y, w1, acc[1][l4*4+1]);
      acc[1][l4*4+2] = dot2u(uu.z, w1, acc[1][l4*4+2]);
      acc[1][l4*4+3] = dot2u(uu.w, w1, acc[1][l4*4+3]);
      acc[2][l4*4+0] = dot2u(uu.x, w2, acc[2][l4*4+0]);
      acc[2][l4*4+1] = dot2u(uu.y, w2, acc[2][l4*4+1]);
      acc[2][l4*4+2] = dot2u(uu.z, w2, acc[2][l4*4+2]);
      acc[2][l4*4+3] = dot2u(uu.w, w2, acc[2][l4*4+3]);
    }
  }
  #pragma unroll
  for (int l=0;l<16;l++){
    int li = l0 + l;
    if (li < L2){
      _Float16* pr = pre + ((size_t)n*L2 + li)*768;
      pr[t]       = (_Float16)acc[0][l];
      pr[t+256]   = (_Float16)acc[1][l];
      pr[t+512]   = (_Float16)acc[2][l];
    }
  }
}

// ---------------- biLSTM scan v4: wh resident in REGISTERS, 1024 thr, G seqs/block ----------
// quarter q = t>>8 handles d2 in [q*24, q*24+24); thread holds 72 packed-f16 weight words.
// Requires N % G == 0.
template<int G>
__global__ __launch_bounds__(1024) void k_lstm4(
    const _Float16* __restrict__ pre, _Float16* __restrict__ r,
    const unsigned int* __restrict__ wh_f, const unsigned int* __restrict__ wh_b,
    int N, int L2){
  __shared__ unsigned int hh2[96*G];     // [d2][s] packed h pairs
  __shared__ float gpart[4*G*768];       // [q][s][gate-row]
  _Float16* hh2h = (_Float16*)hh2;
  int t = threadIdx.x;
  int q = t >> 8, tt = t & 255;
  int dir = blockIdx.y;
  int n0 = blockIdx.x*G;
  const unsigned int* wh = dir ? wh_b : wh_f;
  unsigned int wq[24][3];
  #pragma unroll
  for (int i=0;i<24;i++){
    const unsigned int* wr = wh + (size_t)(q*24+i)*768 + tt;
    wq[i][0] = wr[0]; wq[i][1] = wr[256]; wq[i][2] = wr[512];
  }
  const _Float16* prd = pre + (size_t)dir*(size_t)N*L2*768;
  float cst = 0.f;
  int as = t/192, aj = t - as*192;   // activation mapping, valid for t < 192*G
  for (int idx=t; idx<96*G; idx+=1024) hh2[idx]=0u;
  __syncthreads();

  for (int step=0; step<L2; step++){
    int l = dir ? (L2-1-step) : step;
    float acc[3][G];
    #pragma unroll
    for (int rr=0;rr<3;rr++)
      #pragma unroll
      for (int s=0;s<G;s++) acc[rr][s]=0.f;
    #pragma unroll
    for (int i=0;i<24;i++){
      unsigned int hhv[G];
      #pragma unroll
      for (int s=0;s<G;s++) hhv[s] = hh2[(q*24+i)*G + s];   // broadcast
      #pragma unroll
      for (int rr=0;rr<3;rr++){
        unsigned int w = wq[i][rr];
        #pragma unroll
        for (int s=0;s<G;s++) acc[rr][s] = dot2u(hhv[s], w, acc[rr][s]);
      }
    }
    #pragma unroll
    for (int rr=0;rr<3;rr++)
      #pragma unroll
      for (int s=0;s<G;s++)
        gpart[(q*G+s)*768 + tt + 256*rr] = acc[rr][s];
    __syncthreads();

    if (t < 192*G){
      int n = n0 + as;
      const _Float16* pp = prd + ((size_t)n*L2 + l)*768;
      float gi = (float)pp[aj];
      float gf = (float)pp[aj+192];
      float gg = (float)pp[aj+384];
      float go = (float)pp[aj+576];
      #pragma unroll
      for (int qq=0; qq<4; qq++){
        const float* gp = gpart + (qq*G+as)*768;
        gi += gp[aj]; gf += gp[aj+192]; gg += gp[aj+384]; go += gp[aj+576];
      }
      float ig = sigf(gi), fg = sigf(gf), g2 = tanhf_(gg), og = sigf(go);
      cst = fg*cst + ig*g2;
      float hn = og*tanhf_(cst);
      r[((size_t)n*L2 + l)*384 + dir*192 + aj] = (_Float16)hn;
      hh2h[((aj>>1)*G + as)*2 + (aj&1)] = (_Float16)hn;
    }
    __syncthreads();
  }
}

// ---------------- conv_transpose1d v2 (f16 r input) ----------
__global__ __launch_bounds__(256) void k_convt2(
    const _Float16* __restrict__ r, const float* __restrict__ wt2,
    const float* __restrict__ bias, const float* __restrict__ resid,
    float* __restrict__ dst, int L2, int OL, int mode){
  __shared__ float wsh[384*48];
  int n = blockIdx.y;
  int p0 = blockIdx.x*64;
  int tid = threadIdx.x;
  int pos = p0 + (tid >> 2);
  int cq = tid & 3;
  float4 acc[3];
  acc[0] = make_float4(0,0,0,0); acc[1] = make_float4(0,0,0,0); acc[2] = make_float4(0,0,0,0);

  for (int k=0; k<4; k++){
    const float4* wk4 = (const float4*)(wt2 + (size_t)k*384*48);
    float4* wsh4 = (float4*)wsh;
    for (int i=tid; i<4608; i+=256) wsh4[i] = wk4[i];
    __syncthreads();
    int l = pos - k;
    if (l >= 0 && l < L2){
      const uint2* rr2 = (const uint2*)(r + ((size_t)n*L2 + l)*384);
      const float4* wb = (const float4*)(wsh + cq*12);
      #pragma unroll 4
      for (int ii4=0; ii4<96; ii4++){
        uint2 rp = rr2[ii4];
        v2h p0h = __builtin_bit_cast(v2h, rp.x);
        v2h p1h = __builtin_bit_cast(v2h, rp.y);
        float4 rv = make_float4((float)p0h.x, (float)p0h.y, (float)p1h.x, (float)p1h.y);
        const float4* w0 = wb + (ii4*4)*12;
        float4 wa, wbv, wc;
        wa = w0[0]; wbv = w0[1]; wc = w0[2];
        acc[0].x += rv.x*wa.x; acc[0].y += rv.x*wa.y; acc[0].z += rv.x*wa.z; acc[0].w += rv.x*wa.w;
        acc[1].x += rv.x*wbv.x; acc[1].y += rv.x*wbv.y; acc[1].z += rv.x*wbv.z; acc[1].w += rv.x*wbv.w;
        acc[2].x += rv.x*wc.x; acc[2].y += rv.x*wc.y; acc[2].z += rv.x*wc.z; acc[2].w += rv.x*wc.w;
        wa = w0[12]; wbv = w0[13]; wc = w0[14];
        acc[0].x += rv.y*wa.x; acc[0].y += rv.y*wa.y; acc[0].z += rv.y*wa.z; acc[0].w += rv.y*wa.w;
        acc[1].x += rv.y*wbv.x; acc[1].y += rv.y*wbv.y; acc[1].z += rv.y*wbv.z; acc[1].w += rv.y*wbv.w;
        acc[2].x += rv.y*wc.x; acc[2].y += rv.y*wc.y; acc[2].z += rv.y*wc.z; acc[2].w += rv.y*wc.w;
        wa = w0[24]; wbv = w0[25]; wc = w0[26];
        acc[0].x += rv.z*wa.x; acc[0].y += rv.z*wa.y; acc[0].z += rv.z*wa.z; acc[0].w += rv.z*wa.w;
        acc[1].x += rv.z*wbv.x; acc[1].y += rv.z*wbv.y; acc[1].z += rv.z*wbv.z; acc[1].w += rv.z*wbv.w;
        acc[2].x += rv.z*wc.x; acc[2].y += rv.z*wc.y; acc[2].z += rv.z*wc.z; acc[2].w += rv.z*wc.w;
        wa = w0[36]; wbv = w0[37]; wc = w0[38];
        acc[0].x += rv.w*wa.x; acc[0].y += rv.w*wa.y; acc[0].z += rv.w*wa.z; acc[0].w += rv.w*wa.w;
        acc[1].x += rv.w*wbv.x; acc[1].y += rv.w*wbv.y; acc[1].z += rv.w*wbv.z; acc[1].w += rv.w*wbv.w;
        acc[2].x += rv.w*wc.x; acc[2].y += rv.w*wc.y; acc[2].z += rv.w*wc.z; acc[2].w += rv.w*wc.w;
      }
    }
    __syncthreads();
  }

  if (pos < OL){
    float a[12];
    a[0]=acc[0].x; a[1]=acc[0].y; a[2]=acc[0].z; a[3]=acc[0].w;
    a[4]=acc[1].x; a[5]=acc[1].y; a[6]=acc[1].z; a[7]=acc[1].w;
    a[8]=acc[2].x; a[9]=acc[2].y; a[10]=acc[2].z; a[11]=acc[2].w;
    for (int c12=0; c12<12; c12++){
      int c = cq*12 + c12;
      size_t oidx;
      if (mode==0){ int b = n/250, t = n%250; oidx = (((size_t)b*48+c)*250+t)*65 + pos; }
      else        { int b = n/65,  q = n%65;  oidx = (((size_t)b*48+c)*250+pos)*65 + q; }
      dst[oidx] = a[c12] + bias[c] + resid[oidx];
    }
  }
}

// ---------------- head projection + per-head leaky ----------------
__global__ void k_headproj(const float* __restrict__ bt, const float* __restrict__ w,
                           const float* __restrict__ bias, const float* __restrict__ alpha,
                           float* __restrict__ dst, int dim){
  int i = blockIdx.x*blockDim.x + threadIdx.x;
  int total = 4*2*250*dim*65;
  if (i >= total) return;
  int f = i % 65;
  int e = (i/65) % dim;
  int t = (i/(65*dim)) % 250;
  int b = (i/(65*dim*250)) % 2;
  int h = i/(65*dim*250*2);
  const float* wr = w + (h*dim+e)*48;
  const float* bp = bt + (size_t)b*48*250*65 + (size_t)t*65 + f;
  float acc = bias[h*dim+e];
  for (int c=0;c<48;c++) acc += bp[(size_t)c*250*65]*wr[c];
  if (acc < 0.f) acc *= alpha[h];
  dst[i] = acc;
}

// ---------------- ln_clamp over (e,f) per (h,b,t) block, in place ----------------
__global__ void k_headln(float* __restrict__ buf, const float* __restrict__ g,
                         const float* __restrict__ bt_, int dim){
  __shared__ float r1[256];
  __shared__ float r2[256];
  int bx = blockIdx.x;
  int h = bx/500;
  int n = dim*65;
  float* p = buf + (size_t)bx*n;
  const float* gp = g + h*n;
  const float* bp = bt_ + h*n;
  float s=0.f, ss=0.f;
  for (int k=threadIdx.x; k<n; k+=256){ float v=p[k]; s+=v; ss+=v*v; }
  r1[threadIdx.x]=s; r2[threadIdx.x]=ss; __syncthreads();
  for (int st=128; st>0; st>>=1){
    if (threadIdx.x < st){ r1[threadIdx.x]+=r1[threadIdx.x+st]; r2[threadIdx.x]+=r2[threadIdx.x+st]; }
    __syncthreads();
  }
  float mu = r1[0]/(float)n, var = r2[0]/(float)n - mu*mu;
  float rs = rsqrtf(fmaxf(var, EPSV));
  for (int k=threadIdx.x; k<n; k+=256) p[k] = (p[k]-mu)*rs*gp[k] + bp[k];
}

// ---------------- transpose Kh -> KT[hb][d][s2] ----------------
__global__ void k_ktrans(const float* __restrict__ Kh, float* __restrict__ KT){
  int i = blockIdx.x*blockDim.x + threadIdx.x;
  if (i >= 8*520*250) return;
  int s2 = i % 250;
  int d  = (i/250) % 520;
  int hb = i/(250*520);
  KT[i] = Kh[((size_t)hb*250 + s2)*520 + d];
}

// ---------------- flattened-head attention v2: block per (hb, 10-t tile) ----------------
__global__ __launch_bounds__(256) void k_headattn2(
    const float* __restrict__ Qp, const float* __restrict__ KT,
    const float* __restrict__ Vp, float* __restrict__ Vo){
  __shared__ float qsh[10*520];
  __shared__ float psh[10*250];
  __shared__ float rinv[10];
  int t0 = blockIdx.x*10;
  int hb = blockIdx.y;
  int h = hb >> 1, b = hb & 1;
  int tid = threadIdx.x;
  const float* qbase = Qp + ((size_t)hb*250 + t0)*520;
  for (int i=tid; i<5200; i+=256) qsh[i] = qbase[i];
  __syncthreads();
  const float scale = 0.04385290096535147f; // 1/sqrt(520)
  if (tid < 250){
    float sc[10];
    #pragma unroll
    for (int i=0;i<10;i++) sc[i]=0.f;
    const float* kcol = KT + (size_t)hb*520*250 + tid;
    for (int d=0; d<520; d++){
      float kv = kcol[(size_t)d*250];
      #pragma unroll
      for (int i=0;i<10;i++) sc[i] += qsh[i*520+d]*kv;
    }
    #pragma unroll
    for (int i=0;i<10;i++) psh[i*250+tid] = sc[i]*scale;
  }
  __syncthreads();
  if (tid < 10){
    float m = -1e30f;
    for (int s2=0;s2<250;s2++) m = fmaxf(m, psh[tid*250+s2]);
    float den = 0.f;
    for (int s2=0;s2<250;s2++){
      float e = __expf(psh[tid*250+s2]-m);
      psh[tid*250+s2]=e; den+=e;
    }
    rinv[tid] = 1.0f/den;
  }
  __syncthreads();
  float acc[10][4];
  #pragma unroll
  for (int i=0;i<10;i++)
    #pragma unroll
    for (int s=0;s<4;s++) acc[i][s]=0.f;
  for (int s2=0; s2<250; s2++){
    const float* vrow = Vp + ((size_t)hb*250 + s2)*780;
    float p[10];
    #pragma unroll
    for (int i=0;i<10;i++) p[i] = psh[i*250+s2];
    #pragma unroll
    for (int slot=0; slot<4; slot++){
      int d = tid + slot*256;
      if (d < 780){
        float v = vrow[d];
        #pragma unroll
        for (int i=0;i<10;i++) acc[i][slot] += p[i]*v;
      }
    }
  }
  #pragma unroll
  for (int slot=0; slot<4; slot++){
    int d = tid + slot*256;
    if (d < 780){
      int e = d/65, f = d - e*65;
      #pragma unroll
      for (int i=0;i<10;i++){
        Vo[(((size_t)b*48 + h*12 + e)*250 + (t0+i))*65 + f] = acc[i][slot]*rinv[i];
      }
    }
  }
}

// ---------------- p-projection + leaky ----------------
__global__ void k_pproj(const float* __restrict__ Vo, const float* __restrict__ pw,
                        const float* __restrict__ pb, const float* __restrict__ pa,
                        float* __restrict__ pj){
  int i = blockIdx.x*blockDim.x + threadIdx.x;
  if (i >= 2*48*250*65) return;
  int f = i % 65;
  int t = (i/65) % 250;
  int o = (i/(65*250)) % 48;
  int b = i/(65*250*48);
  const float* vp = Vo + (size_t)b*48*250*65 + (size_t)t*65 + f;
  const float* wr = pw + o*48;
  float acc = pb[o];
  for (int c=0;c<48;c++) acc += vp[(size_t)c*250*65]*wr[c];
  if (acc < 0.f) acc *= pa[0];
  pj[i] = acc;
}

// ---------------- ln_clamp over (c,f) per (b,t) + residual ----------------
__global__ void k_pln(const float* __restrict__ pj, const float* __restrict__ pg,
                      const float* __restrict__ pbt, const float* __restrict__ inter,
                      float* __restrict__ outb){
  __shared__ float r1[256];
  __shared__ float r2[256];
  int bx = blockIdx.x;
  int t = bx % 250, b = bx/250;
  const float* base = pj + (size_t)b*48*250*65 + (size_t)t*65;
  float s=0.f, ss=0.f;
  for (int k=threadIdx.x; k<3120; k+=256){
    int c = k/65, f = k%65;
    float v = base[(size_t)c*250*65 + f];
    s+=v; ss+=v*v;
  }
  r1[threadIdx.x]=s; r2[threadIdx.x]=ss; __syncthreads();
  for (int st=128; st>0; st>>=1){
    if (threadIdx.x<st){ r1[threadIdx.x]+=r1[threadIdx.x+st]; r2[threadIdx.x]+=r2[threadIdx.x+st]; }
    __syncthreads();
  }
  float mu = r1[0]*(1.0f/3120.0f), var = r2[0]*(1.0f/3120.0f) - mu*mu;
  float rs = rsqrtf(fmaxf(var, EPSV));
  for (int k=threadIdx.x; k<3120; k+=256){
    int c = k/65, f = k%65;
    size_t idx = (((size_t)b*48+c)*250 + t)*65 + f;
    float v = pj[idx];
    outb[idx] = (v-mu)*rs*pg[c*65+f] + pbt[c*65+f] + inter[idx];
  }
}

// ---------------- fin 1x1: (B,48,...) -> (B,384,...) ----------------
__global__ void k_fin(const float* __restrict__ outb, const float* __restrict__ w,
                      const float* __restrict__ bias, float* __restrict__ pi){
  int i = blockIdx.x*blockDim.x + threadIdx.x;
  if (i >= 2*384*250*65) return;
  int f = i % 65;
  int t = (i/65) % 250;
  int o = (i/(65*250)) % 384;
  int b = i/(65*250*384);
  const float* xp = outb + (size_t)b*48*250*65 + (size_t)t*65 + f;
  const float* wr = w + o*48;
  float acc = bias[o];
  for (int c=0;c<48;c++) acc += xp[(size_t)c*250*65]*wr[c];
  pi[i] = acc;
}

// ---------------- depthwise 3x3 both halves + gelu-gate ----------------
__global__ void k_dwg(const float* __restrict__ pi, const float* __restrict__ dw,
                      const float* __restrict__ db, float* __restrict__ gbuf){
  int i = blockIdx.x*blockDim.x + threadIdx.x;
  if (i >= 2*192*250*65) return;
  int f = i % 65;
  int t = (i/65) % 250;
  int j = (i/(65*250)) % 192;
  int b = i/(65*250*192);
  float x12[2];
  for (int half=0; half<2; half++){
    int ch = j + half*192;
    const float* base = pi + ((size_t)b*384 + ch)*250*65;
    const float* wr = dw + ch*9;
    float acc = db[ch];
    for (int dt=-1; dt<=1; dt++){
      int tt = t+dt;
      if (tt<0||tt>=250) continue;
      for (int df=-1; df<=1; df++){
        int ff = f+df;
        if (ff<0||ff>=65) continue;
        acc += base[(size_t)tt*65+ff]*wr[(dt+1)*3 + (df+1)];
      }
    }
    x12[half]=acc;
  }
  float x1 = x12[0];
  float g = 0.5f*x1*(1.0f+erff(x1*0.70710678118654752f));
  gbuf[i] = g * x12[1];
}

// ---------------- final 1x1 (192->48) + residual -> d_out ----------------
__global__ void k_final(const float* __restrict__ gbuf, const float* __restrict__ w,
                        const float* __restrict__ bias, const float* __restrict__ outb,
                        float* __restrict__ dout){
  int i = blockIdx.x*blockDim.x + threadIdx.x;
  if (i >= 2*48*250*65) return;
  int f = i % 65;
  int t = (i/65) % 250;
  int o = (i/(65*250)) % 48;
  int b = i/(65*250*48);
  const float* gp = gbuf + (size_t)b*192*250*65 + (size_t)t*65 + f;
  const float* wr = w + o*192;
  float acc = bias[o];
  for (int j=0;j<192;j++) acc += gp[(size_t)j*250*65]*wr[j];
  dout[i] = acc + outb[i];
}

extern "C" void kernel_launch(void* const* d_in, const int* in_sizes, int n_in,
                              void* d_out, int out_size, void* d_ws, size_t ws_size,
                              hipStream_t stream) {
  (void)in_sizes; (void)n_in; (void)out_size; (void)ws_size;
  auto in = [&](int i){ return (const float*)d_in[i]; };
  const float* x        = in(0);
  const float* af_in_w  = in(1);  const float* af_in_b  = in(2);
  const float* af_out_w = in(3);  const float* af_out_b = in(4);
  const float* at_in_w  = in(5);  const float* at_in_b  = in(6);
  const float* at_out_w = in(7);  const float* at_out_b = in(8);
  const float* naf_g = in(9),  *naf_b = in(10), *nat_g = in(11), *nat_b = in(12);
  const float* intra_ng = in(13), *intra_nb = in(14), *inter_ng = in(15), *inter_nb = in(16);
  const float* intra_wif = in(17), *intra_whf = in(18), *intra_bif = in(19), *intra_bhf = in(20);
  const float* intra_wib = in(21), *intra_whb = in(22), *intra_bib = in(23), *intra_bhb = in(24);
  const float* inter_wif = in(25), *inter_whf = in(26), *inter_bif = in(27), *inter_bhf = in(28);
  const float* inter_wib = in(29), *inter_whb = in(30), *inter_bib = in(31), *inter_bhb = in(32);
  const float* il_w = in(33), *il_b = in(34), *itl_w = in(35), *itl_b = in(36);
  const float* qw = in(37), *qb = in(38), *qa = in(39), *qg = in(40), *qbt = in(41);
  const float* kw = in(42), *kb = in(43), *ka = in(44), *kg = in(45), *kbt = in(46);
  const float* vw = in(47), *vb = in(48), *va = in(49), *vg = in(50), *vbt = in(51);
  const float* pw = in(52), *pb = in(53), *pa = in(54), *pg = in(55), *pbt = in(56);
  const float* fin_w = in(57), *fin_b = in(58), *fdw_w = in(59), *fdw_b = in(60);
  const float* fout_w = in(61), *fout_b = in(62);

  float* ws = (float*)d_ws;
  float* buf_intra = ws + 0;                        // 1,560,000
  float* buf_bt    = ws + 1560000;                  // 1,560,000
  float* buf_out   = ws + 3120000;                  // 1,560,000
  unsigned int* wpk = (unsigned int*)(ws + 4680000);// 8 * 73,728 words
  float* wtc       = ws + 5269824;                  // 2 * 73,728 words
  float* scr       = ws + 5417280;                  // arena
  // staging (dead before pre-gates)
  float* s_seq2 = scr;                              // 1,560,000
  float* s_seq  = scr + 1560000;                    // 1,560,000
  float* s_qkv  = scr + 3120000;                    // 4,680,000
  float* s_att  = scr + 7800000;                    // 1,560,000
  // lstm buffers
  _Float16* s_pre = (_Float16*)(scr + 1560000);     // up to 49,320,960 halfs (2 dirs)
  _Float16* s_r   = (_Float16*)(scr + 26220480);    // up to 12,330,240 halfs
  // phase3 aliases
  float* s_Qh = scr;                                // 1,040,000
  float* s_Kh = scr + 1040000;                      // 1,040,000
  float* s_Vh = scr + 2080000;                      // 1,560,000
  float* s_Vo = scr + 3640000;                      // 1,560,000
  float* s_pj = scr + 5200000;                      // 1,560,000
  float* s_KT = scr + 6760000;                      // 1,040,000
  // phase4 aliases
  float* s_pi = scr;
  float* s_g  = scr + 12480000;

  const int thr = 256;
  auto cdiv = [](int a, int b){ return (a+b-1)/b; };

  // ---------------- weight prep ----------------
  k_wpack<<<cdiv(73728,thr),thr,0,stream>>>(intra_wif, wpk + 0*73728);
  k_wpack<<<cdiv(73728,thr),thr,0,stream>>>(intra_whf, wpk + 1*73728);
  k_wpack<<<cdiv(73728,thr),thr,0,stream>>>(intra_wib, wpk + 2*73728);
  k_wpack<<<cdiv(73728,thr),thr,0,stream>>>(intra_whb, wpk + 3*73728);
  k_wpack<<<cdiv(73728,thr),thr,0,stream>>>(inter_wif, wpk + 4*73728);
  k_wpack<<<cdiv(73728,thr),thr,0,stream>>>(inter_whf, wpk + 5*73728);
  k_wpack<<<cdiv(73728,thr),thr,0,stream>>>(inter_wib, wpk + 6*73728);
  k_wpack<<<cdiv(73728,thr),thr,0,stream>>>(inter_whb, wpk + 7*73728);
  k_wtc<<<cdiv(73728,thr),thr,0,stream>>>(il_w,  wtc + 0*73728);
  k_wtc<<<cdiv(73728,thr),thr,0,stream>>>(itl_w, wtc + 1*73728);

  // ---------------- Phase 1: intra (along Q): N=500, L2=62, SL=65 ----------------
  k_ln_chan<<<cdiv(2*250*65,thr), thr, 0, stream>>>(x, s_seq, intra_ng, intra_nb, 0);
  k_qkv<<<cdiv(500*65*144,thr), thr, 0, stream>>>(s_seq, af_in_w, af_in_b, s_qkv, 500*65);
  k_mha<<<dim3(500,4), 256, 0, stream>>>(s_qkv, s_att, 500, 65);
  k_projres<<<cdiv(500*65*48,thr), thr, 0, stream>>>(s_att, s_seq, af_out_w, af_out_b, s_seq2, 500*65);
  k_rowln<<<cdiv(32500,thr), thr, 0, stream>>>(s_seq2, naf_g, naf_b, 32500);
  {
    const size_t dstr = (size_t)500*62*768;
    k_pregates<<<dim3(4,500), 256, 0, stream>>>(s_seq2, wpk+0*73728, intra_bif, intra_bhf, s_pre,        62, 65);
    k_pregates<<<dim3(4,500), 256, 0, stream>>>(s_seq2, wpk+2*73728, intra_bib, intra_bhb, s_pre + dstr, 62, 65);
  }
  k_lstm4<4><<<dim3(125,2), 1024, 0, stream>>>(s_pre, s_r, wpk+1*73728, wpk+3*73728, 500, 62);
  k_convt2<<<dim3(2,500), 256, 0, stream>>>(s_r, wtc+0*73728, il_b, x, buf_intra, 62, 65, 0);

  // ---------------- Phase 2: inter (along T): N=130, L2=247, SL=250 ----------------
  k_ln_chan<<<cdiv(2*250*65,thr),thr,0,stream>>>(buf_intra, s_seq, inter_ng, inter_nb, 1);
  k_qkv<<<cdiv(130*250*144,thr),thr,0,stream>>>(s_seq, at_in_w, at_in_b, s_qkv, 130*250);
  k_mha<<<dim3(130,4), 256, 0, stream>>>(s_qkv, s_att, 130, 250);
  k_projres<<<cdiv(130*250*48,thr),thr,0,stream>>>(s_att, s_seq, at_out_w, at_out_b, s_seq2, 130*250);
  k_rowln<<<cdiv(32500,thr),thr,0,stream>>>(s_seq2, nat_g, nat_b, 32500);
  {
    const size_t dstr = (size_t)130*247*768;
    k_pregates<<<dim3(16,130), 256, 0, stream>>>(s_seq2, wpk+4*73728, inter_bif, inter_bhf, s_pre,        247, 250);
    k_pregates<<<dim3(16,130), 256, 0, stream>>>(s_seq2, wpk+6*73728, inter_bib, inter_bhb, s_pre + dstr, 247, 250);
  }
  k_lstm4<2><<<dim3(65,2), 1024, 0, stream>>>(s_pre, s_r, wpk+5*73728, wpk+7*73728, 130, 247);
  k_convt2<<<dim3(4,130), 256, 0, stream>>>(s_r, wtc+1*73728, itl_b, buf_intra, buf_bt, 247, 250, 1);

  // ---------------- Phase 3: flattened-head attention ----------------
  k_headproj<<<cdiv(4*2*250*8*65,thr),thr,0,stream>>>(buf_bt, qw, qb, qa, s_Qh, 8);
  k_headln<<<2000,256,0,stream>>>(s_Qh, qg, qbt, 8);
  k_headproj<<<cdiv(4*2*250*8*65,thr),thr,0,stream>>>(buf_bt, kw, kb, ka, s_Kh, 8);
  k_headln<<<2000,256,0,stream>>>(s_Kh, kg, kbt, 8);
  k_headproj<<<cdiv(4*2*250*12*65,thr),thr,0,stream>>>(buf_bt, vw, vb, va, s_Vh, 12);
  k_headln<<<2000,256,0,stream>>>(s_Vh, vg, vbt, 12);
  k_ktrans<<<cdiv(8*520*250,thr),thr,0,stream>>>(s_Kh, s_KT);
  k_headattn2<<<dim3(25,8), 256, 0, stream>>>(s_Qh, s_KT, s_Vh, s_Vo);
  k_pproj<<<cdiv(2*48*250*65,thr),thr,0,stream>>>(s_Vo, pw, pb, pa, s_pj);
  k_pln<<<500,256,0,stream>>>(s_pj, pg, pbt, buf_bt, buf_out);

  // ---------------- Phase 4: FFN ----------------
  k_fin<<<cdiv(2*384*250*65,thr),thr,0,stream>>>(buf_out, fin_w, fin_b, s_pi);
  k_dwg<<<cdiv(2*192*250*65,thr),thr,0,stream>>>(s_pi, fdw_w, fdw_b, s_g);
  k_final<<<cdiv(2*48*250*65,thr),thr,0,stream>>>(s_g, fout_w, fout_b, buf_out, (float*)d_out);
}

// Round 5
// 2561.958 us; speedup vs baseline: 5.9349x; 1.0982x over previous
//
#include <hip/hip_runtime.h>
#include <math.h>

#define EPSV 1e-5f

typedef _Float16 v2h __attribute__((ext_vector_type(2)));

__device__ __forceinline__ float sigf(float x){ return 1.0f/(1.0f+__expf(-x)); }
__device__ __forceinline__ float tanhf_(float x){
  float c = fminf(fmaxf(x,-10.f),10.f);
  float e = __expf(2.0f*c);
  return (e-1.0f)/(e+1.0f);
}

__device__ __forceinline__ float dot2u(unsigned int a, unsigned int b, float c){
#if __has_builtin(__builtin_amdgcn_fdot2)
  v2h av = __builtin_bit_cast(v2h, a);
  v2h bv = __builtin_bit_cast(v2h, b);
  return __builtin_amdgcn_fdot2(av, bv, c, false);
#else
  v2h av = __builtin_bit_cast(v2h, a);
  v2h bv = __builtin_bit_cast(v2h, b);
  return c + (float)av.x*(float)bv.x + (float)av.y*(float)bv.y;
#endif
}

// ---------------- LN over channel dim -> channel-last seq ----------------
__global__ void k_ln_chan(const float* __restrict__ src, float* __restrict__ dst,
                          const float* __restrict__ g, const float* __restrict__ bb, int mode){
  int i = blockIdx.x*blockDim.x + threadIdx.x;
  const int total = 2*250*65;
  if (i >= total) return;
  int q = i % 65; int t = (i/65) % 250; int b = i/(65*250);
  const float* p = src + (size_t)b*48*250*65 + (size_t)t*65 + q;
  float s=0.f, ss=0.f;
  for (int c=0;c<48;c++){ float v = p[(size_t)c*250*65]; s+=v; ss+=v*v; }
  float mu = s*(1.0f/48.0f);
  float var = ss*(1.0f/48.0f) - mu*mu;
  float rs = rsqrtf(fmaxf(var, EPSV));
  float* d = (mode==0) ? dst + ((size_t)(b*250+t)*65 + q)*48
                       : dst + ((size_t)(b*65+q)*250 + t)*48;
  for (int c=0;c<48;c++){ float v = p[(size_t)c*250*65]; d[c] = (v-mu)*rs*g[c] + bb[c]; }
}

// ---------------- qkv = seq @ in_w.T + in_b ----------------
__global__ void k_qkv(const float* __restrict__ seq, const float* __restrict__ w,
                      const float* __restrict__ bias, float* __restrict__ qkv, int NL){
  int i = blockIdx.x*blockDim.x + threadIdx.x;
  if (i >= NL*144) return;
  int j = i % 144; int nl = i / 144;
  const float* srow = seq + (size_t)nl*48;
  const float* wrow = w + j*48;
  float acc = bias[j];
  for (int c=0;c<48;c++) acc += srow[c]*wrow[c];
  qkv[i] = acc;
}

// ---------------- MHA core ----------------
__global__ void k_mha(const float* __restrict__ qkv, float* __restrict__ att, int N, int L){
  __shared__ float shq[250*12];
  __shared__ float shk[250*12];
  __shared__ float shv[250*12];
  int n = blockIdx.x, h = blockIdx.y;
  const float* base = qkv + (size_t)n*L*144 + h*12;
  for (int i = threadIdx.x; i < L*12; i += blockDim.x){
    int l = i/12, d = i%12;
    shq[i] = base[(size_t)l*144 + d];
    shk[i] = base[(size_t)l*144 + 48 + d];
    shv[i] = base[(size_t)l*144 + 96 + d];
  }
  __syncthreads();
  const float scale = 0.28867513459481287f;
  for (int r = threadIdx.x; r < L; r += blockDim.x){
    float m = -1e30f, den = 0.0f, o[12];
    for (int d=0; d<12; d++) o[d]=0.0f;
    const float* qr = shq + r*12;
    for (int j=0; j<L; j++){
      const float* kr = shk + j*12;
      float s = 0.f;
      for (int d=0; d<12; d++) s += qr[d]*kr[d];
      s *= scale;
      if (s > m){
        float corr = __expf(m - s);
        den *= corr;
        for (int d=0; d<12; d++) o[d] *= corr;
        m = s;
      }
      float e = __expf(s - m);
      den += e;
      const float* vr = shv + j*12;
      for (int d=0; d<12; d++) o[d] += e*vr[d];
    }
    float inv = 1.0f/den;
    float* outp = att + ((size_t)n*L + r)*48 + h*12;
    for (int d=0; d<12; d++) outp[d] = o[d]*inv;
  }
}

// ---------------- out proj + residual ----------------
__global__ void k_projres(const float* __restrict__ att, const float* __restrict__ seq,
                          const float* __restrict__ w, const float* __restrict__ bias,
                          float* __restrict__ dst, int NL){
  int i = blockIdx.x*blockDim.x + threadIdx.x;
  if (i >= NL*48) return;
  int o = i % 48; int nl = i/48;
  const float* ar = att + (size_t)nl*48;
  const float* wr = w + o*48;
  float acc = bias[o] + seq[i];
  for (int c=0;c<48;c++) acc += ar[c]*wr[c];
  dst[i] = acc;
}

// ---------------- torch_ln over last dim (48), in place ----------------
__global__ void k_rowln(float* __restrict__ buf, const float* __restrict__ g,
                        const float* __restrict__ bb, int NL){
  int nl = blockIdx.x*blockDim.x + threadIdx.x;
  if (nl >= NL) return;
  float* p = buf + (size_t)nl*48;
  float s=0.f, ss=0.f;
  for (int c=0;c<48;c++){ float v=p[c]; s+=v; ss+=v*v; }
  float mu = s*(1.0f/48.0f);
  float var = ss*(1.0f/48.0f) - mu*mu;
  float rs = rsqrtf(var + EPSV);
  for (int c=0;c<48;c++) p[c] = (p[c]-mu)*rs*g[c] + bb[c];
}

// ---------------- fused weight prep: 8x lstm wpack + 2x convT f16-pack ----------------
// wpack: fp32 [768][192] -> half2-uint [96][768]
// convpack: fp32 [384][48][4] -> uint [k][ii2][48] packing (w[2*ii2][c][k], w[2*ii2+1][c][k])
__global__ void k_prep(const float* __restrict__ s0, const float* __restrict__ s1,
                       const float* __restrict__ s2, const float* __restrict__ s3,
                       const float* __restrict__ s4, const float* __restrict__ s5,
                       const float* __restrict__ s6, const float* __restrict__ s7,
                       const float* __restrict__ c0, const float* __restrict__ c1,
                       unsigned int* __restrict__ wpk, unsigned int* __restrict__ wtp){
  int i = blockIdx.x*blockDim.x + threadIdx.x;
  if (i < 589824){
    int seg = i/73728, off = i - seg*73728;
    const float* w = (seg==0)?s0:(seg==1)?s1:(seg==2)?s2:(seg==3)?s3:(seg==4)?s4:(seg==5)?s5:(seg==6)?s6:s7;
    int g = off % 768, d2 = off / 768;
    v2h v; v.x = (_Float16)w[g*192 + 2*d2]; v.y = (_Float16)w[g*192 + 2*d2 + 1];
    wpk[(size_t)seg*73728 + (size_t)d2*768 + g] = __builtin_bit_cast(unsigned int, v);
  } else if (i < 589824 + 2*36864){
    int j = i - 589824;
    int seg = j/36864, off = j - seg*36864;
    const float* w = seg ? c1 : c0;
    int c = off % 48; int ii2 = (off/48) % 192; int k = off/(48*192);
    v2h v;
    v.x = (_Float16)w[(2*ii2)*192 + c*4 + k];
    v.y = (_Float16)w[(2*ii2+1)*192 + c*4 + k];
    wtp[(size_t)seg*36864 + off] = __builtin_bit_cast(unsigned int, v);
  }
}

// ---------------- pre-gates GEMM: pre[n][l][g] = u.wi^T + bi + bh (f16 out) ----------------
__global__ __launch_bounds__(256) void k_pregates(
    const float* __restrict__ seq2, const unsigned int* __restrict__ wi,
    const float* __restrict__ bi, const float* __restrict__ bh,
    _Float16* __restrict__ pre, int L2, int SL){
  __shared__ unsigned int ut[96*16];
  int n = blockIdx.y;
  int l0 = blockIdx.x*16;
  int t = threadIdx.x;
  for (int idx=t; idx<1536; idx+=256){
    int l = idx & 15, d2 = idx >> 4;
    int li = l0 + l;
    int c = d2 >> 1, k0 = (d2 & 1)*2;
    float u0=0.f, u1=0.f;
    if (li < L2){
      const float* p = seq2 + ((size_t)n*SL + li)*48;
      u0 = p[k0*48 + c];
      u1 = p[(k0+1)*48 + c];
    }
    v2h v; v.x=(_Float16)u0; v.y=(_Float16)u1;
    ut[d2*16 + l] = __builtin_bit_cast(unsigned int, v);
  }
  __syncthreads();
  float acc[3][16];
  float b0 = bi[t] + bh[t];
  float b1 = bi[t+256] + bh[t+256];
  float b2 = bi[t+512] + bh[t+512];
  #pragma unroll
  for (int l=0;l<16;l++){ acc[0][l]=b0; acc[1][l]=b1; acc[2][l]=b2; }
  #pragma unroll 4
  for (int d2=0; d2<96; d2++){
    unsigned int w0 = wi[(size_t)d2*768 + t];
    unsigned int w1 = wi[(size_t)d2*768 + t + 256];
    unsigned int w2 = wi[(size_t)d2*768 + t + 512];
    const uint4* u4 = (const uint4*)(ut + d2*16);
    #pragma unroll
    for (int l4=0; l4<4; l4++){
      uint4 uu = u4[l4];
      acc[0][l4*4+0] = dot2u(uu.x, w0, acc[0][l4*4+0]);
      acc[0][l4*4+1] = dot2u(uu.y, w0, acc[0][l4*4+1]);
      acc[0][l4*4+2] = dot2u(uu.z, w0, acc[0][l4*4+2]);
      acc[0][l4*4+3] = dot2u(uu.w, w0, acc[0][l4*4+3]);
      acc[1][l4*4+0] = dot2u(uu.x, w1, acc[1][l4*4+0]);
      acc[1][l4*4+1] = dot2u(uu.y, w1, acc[1][l4*4+1]);
      acc[1][l4*4+2] = dot2u(uu.z, w1, acc[1][l4*4+2]);
      acc[1][l4*4+3] = dot2u(uu.w, w1, acc[1][l4*4+3]);
      acc[2][l4*4+0] = dot2u(uu.x, w2, acc[2][l4*4+0]);
      acc[2][l4*4+1] = dot2u(uu.y, w2, acc[2][l4*4+1]);
      acc[2][l4*4+2] = dot2u(uu.z, w2, acc[2][l4*4+2]);
      acc[2][l4*4+3] = dot2u(uu.w, w2, acc[2][l4*4+3]);
    }
  }
  #pragma unroll
  for (int l=0;l<16;l++){
    int li = l0 + l;
    if (li < L2){
      _Float16* pr = pre + ((size_t)n*L2 + li)*768;
      pr[t]       = (_Float16)acc[0][l];
      pr[t+256]   = (_Float16)acc[1][l];
      pr[t+512]   = (_Float16)acc[2][l];
    }
  }
}

// ---------------- biLSTM scan v5: reg-resident wh, pre prefetch, rT2 packed output -------
// rT2 layout: uint pairs rT2[(n*192 + dir*96 + ii2)*L2 + l] = (h[2*ii2], h[2*ii2+1]) f16.
// Requires N % G == 0.
template<int G>
__global__ __launch_bounds__(1024) void k_lstm5(
    const _Float16* __restrict__ pre, unsigned int* __restrict__ rT2,
    const unsigned int* __restrict__ wh_f, const unsigned int* __restrict__ wh_b,
    int N, int L2){
  __shared__ unsigned int hh2[96*G];     // [j2][s] packed h pairs
  __shared__ float gpart[4*G*768];       // [q][s][gate-row]
  _Float16* hh2h = (_Float16*)hh2;
  int t = threadIdx.x;
  int q = t >> 8, tt = t & 255;
  int dir = blockIdx.y;
  int n0 = blockIdx.x*G;
  const unsigned int* wh = dir ? wh_b : wh_f;
  unsigned int wq[24][3];
  #pragma unroll
  for (int i=0;i<24;i++){
    const unsigned int* wr = wh + (size_t)(q*24+i)*768 + tt;
    wq[i][0] = wr[0]; wq[i][1] = wr[256]; wq[i][2] = wr[512];
  }
  const _Float16* prd = pre + (size_t)dir*(size_t)N*L2*768;
  float cst = 0.f;
  int as = t/192, aj = t - as*192;
  bool actv = (t < 192*G);
  const unsigned short* pbase = (const unsigned short*)prd;
  if (actv) pbase = (const unsigned short*)(prd + ((size_t)(n0+as)*L2)*768) + aj;
  for (int idx=t; idx<96*G; idx+=1024) hh2[idx]=0u;
  __syncthreads();

  for (int step=0; step<L2; step++){
    int l = dir ? (L2-1-step) : step;
    // prefetch pre (raw, converted after barrier)
    unsigned short p0=0,p1=0,p2=0,p3=0;
    if (actv){
      const unsigned short* pp = pbase + (size_t)l*768;
      p0 = pp[0]; p1 = pp[192]; p2 = pp[384]; p3 = pp[576];
    }
    float acc0[G], acc1[G], acc2[G];
    #pragma unroll
    for (int s=0;s<G;s++){ acc0[s]=0.f; acc1[s]=0.f; acc2[s]=0.f; }
    #pragma unroll
    for (int i=0;i<24;i++){
      unsigned int hhv[G];
      if (G==4){
        uint4 hv = ((const uint4*)hh2)[q*24+i];
        hhv[0]=hv.x; hhv[1]=hv.y; hhv[2]=hv.z; hhv[3]=hv.w;
      } else if (G==2){
        uint2 hv = ((const uint2*)hh2)[q*24+i];
        hhv[0]=hv.x; hhv[1]=hv.y;
      } else {
        hhv[0] = hh2[q*24+i];
      }
      unsigned int w0 = wq[i][0], w1 = wq[i][1], w2 = wq[i][2];
      #pragma unroll
      for (int s=0;s<G;s++){
        acc0[s] = dot2u(hhv[s], w0, acc0[s]);
        acc1[s] = dot2u(hhv[s], w1, acc1[s]);
        acc2[s] = dot2u(hhv[s], w2, acc2[s]);
      }
    }
    #pragma unroll
    for (int s=0;s<G;s++){
      gpart[(q*G+s)*768 + tt]       = acc0[s];
      gpart[(q*G+s)*768 + tt + 256] = acc1[s];
      gpart[(q*G+s)*768 + tt + 512] = acc2[s];
    }
    __syncthreads();

    if (actv){
      float gi = (float)__builtin_bit_cast(_Float16, p0);
      float gf = (float)__builtin_bit_cast(_Float16, p1);
      float gg = (float)__builtin_bit_cast(_Float16, p2);
      float go = (float)__builtin_bit_cast(_Float16, p3);
      #pragma unroll
      for (int qq=0; qq<4; qq++){
        const float* gp = gpart + (qq*G+as)*768;
        gi += gp[aj]; gf += gp[aj+192]; gg += gp[aj+384]; go += gp[aj+576];
      }
      float ig = sigf(gi), fg = sigf(gf), g2 = tanhf_(gg), og = sigf(go);
      cst = fg*cst + ig*g2;
      float hn = og*tanhf_(cst);
      hh2h[((aj>>1)*G + as)*2 + (aj&1)] = (_Float16)hn;
    }
    __syncthreads();

    // store packed h pairs (transposed layout) from LDS
    if (t < 96*G){
      int s = t/96, ii2 = t - s*96;
      unsigned int v = hh2[ii2*G + s];
      rT2[((size_t)(n0+s)*192 + dir*96 + ii2)*L2 + l] = v;
    }
  }
}

// ---------------- conv_transpose1d v4: scalar (SMEM) weights, coalesced rT2 reads -------
// wave w handles c in [w*12, w*12+12); lane = pos offset within 64-tile.
__global__ __launch_bounds__(256) void k_convt4(
    const unsigned int* __restrict__ rT2, const unsigned int* __restrict__ wtp,
    const float* __restrict__ bias, const float* __restrict__ resid,
    float* __restrict__ dst, int L2, int OL, int mode){
  int n = blockIdx.y;
  int pos = blockIdx.x*64 + (threadIdx.x & 63);
  int cq = __builtin_amdgcn_readfirstlane((int)(threadIdx.x >> 6));
  float acc[12];
  #pragma unroll
  for (int c=0;c<12;c++) acc[c]=0.f;
  const unsigned int* rbase = rT2 + (size_t)n*192*L2;
  for (int k=0;k<4;k++){
    int l = pos - k;
    bool v = (l>=0) && (l<L2);
    int lc = v ? l : 0;
    const unsigned int* wk = wtp + (size_t)k*192*48 + cq*12;
    #pragma unroll 4
    for (int ii2=0; ii2<192; ii2++){
      unsigned int rp = v ? rbase[(size_t)ii2*L2 + lc] : 0u;
      const unsigned int* wrow = wk + ii2*48;
      #pragma unroll
      for (int c=0;c<12;c++) acc[c] = dot2u(rp, wrow[c], acc[c]);
    }
  }
  if (pos < OL){
    for (int c12=0;c12<12;c12++){
      int c = cq*12 + c12;
      size_t oidx;
      if (mode==0){ int b=n/250, t=n%250; oidx = (((size_t)b*48+c)*250+t)*65+pos; }
      else        { int b=n/65,  qq=n%65; oidx = (((size_t)b*48+c)*250+pos)*65+qq; }
      dst[oidx] = acc[c12] + bias[c] + resid[oidx];
    }
  }
}

// ---------------- fused head projection + leaky + ln_clamp (+optional KT write) ----------
__global__ __launch_bounds__(256) void k_hproj(
    const float* __restrict__ bt, const float* __restrict__ w,
    const float* __restrict__ bias, const float* __restrict__ alpha,
    const float* __restrict__ g, const float* __restrict__ beta,
    float* __restrict__ dst, int dim, int kt_mode){
  __shared__ float ybuf[780];
  __shared__ float r1[256];
  __shared__ float r2[256];
  int bx = blockIdx.x;          // (h*2+b)*250+t
  int h = bx/500; int rem = bx - h*500; int b = rem/250; int t = rem - b*250;
  int ny = dim*65;
  int tid = threadIdx.x;
  const float* bbase = bt + (size_t)b*48*250*65 + (size_t)t*65;
  float al = alpha[h];
  float s=0.f, ss=0.f;
  for (int kidx=tid; kidx<ny; kidx+=256){
    int e = kidx/65, f = kidx - e*65;
    const float* wr = w + (h*dim+e)*48;
    float acc = bias[h*dim+e];
    for (int c=0;c<48;c++) acc += bbase[(size_t)c*250*65 + f]*wr[c];
    if (acc < 0.f) acc *= al;
    ybuf[kidx] = acc; s += acc; ss += acc*acc;
  }
  r1[tid]=s; r2[tid]=ss; __syncthreads();
  for (int st=128; st>0; st>>=1){
    if (tid<st){ r1[tid]+=r1[tid+st]; r2[tid]+=r2[tid+st]; }
    __syncthreads();
  }
  float mu = r1[0]/(float)ny, var = r2[0]/(float)ny - mu*mu;
  float rs = rsqrtf(fmaxf(var, EPSV));
  for (int kidx=tid; kidx<ny; kidx+=256){
    float y = (ybuf[kidx]-mu)*rs*g[h*ny+kidx] + beta[h*ny+kidx];
    if (kt_mode) dst[((size_t)(h*2+b)*520 + kidx)*250 + t] = y;
    else         dst[(size_t)bx*ny + kidx] = y;
  }
}

// ---------------- flattened-head attention v2: block per (hb, 10-t tile) ----------------
__global__ __launch_bounds__(256) void k_headattn2(
    const float* __restrict__ Qp, const float* __restrict__ KT,
    const float* __restrict__ Vp, float* __restrict__ Vo){
  __shared__ float qsh[10*520];
  __shared__ float psh[10*250];
  __shared__ float rinv[10];
  int t0 = blockIdx.x*10;
  int hb = blockIdx.y;
  int h = hb >> 1, b = hb & 1;
  int tid = threadIdx.x;
  const float* qbase = Qp + ((size_t)hb*250 + t0)*520;
  for (int i=tid; i<5200; i+=256) qsh[i] = qbase[i];
  __syncthreads();
  const float scale = 0.04385290096535147f; // 1/sqrt(520)
  if (tid < 250){
    float sc[10];
    #pragma unroll
    for (int i=0;i<10;i++) sc[i]=0.f;
    const float* kcol = KT + (size_t)hb*520*250 + tid;
    for (int d=0; d<520; d++){
      float kv = kcol[(size_t)d*250];
      #pragma unroll
      for (int i=0;i<10;i++) sc[i] += qsh[i*520+d]*kv;
    }
    #pragma unroll
    for (int i=0;i<10;i++) psh[i*250+tid] = sc[i]*scale;
  }
  __syncthreads();
  if (tid < 10){
    float m = -1e30f;
    for (int s2=0;s2<250;s2++) m = fmaxf(m, psh[tid*250+s2]);
    float den = 0.f;
    for (int s2=0;s2<250;s2++){
      float e = __expf(psh[tid*250+s2]-m);
      psh[tid*250+s2]=e; den+=e;
    }
    rinv[tid] = 1.0f/den;
  }
  __syncthreads();
  float acc[10][4];
  #pragma unroll
  for (int i=0;i<10;i++)
    #pragma unroll
    for (int s=0;s<4;s++) acc[i][s]=0.f;
  for (int s2=0; s2<250; s2++){
    const float* vrow = Vp + ((size_t)hb*250 + s2)*780;
    float p[10];
    #pragma unroll
    for (int i=0;i<10;i++) p[i] = psh[i*250+s2];
    #pragma unroll
    for (int slot=0; slot<4; slot++){
      int d = tid + slot*256;
      if (d < 780){
        float v = vrow[d];
        #pragma unroll
        for (int i=0;i<10;i++) acc[i][slot] += p[i]*v;
      }
    }
  }
  #pragma unroll
  for (int slot=0; slot<4; slot++){
    int d = tid + slot*256;
    if (d < 780){
      int e = d/65, f = d - e*65;
      #pragma unroll
      for (int i=0;i<10;i++){
        Vo[(((size_t)b*48 + h*12 + e)*250 + (t0+i))*65 + f] = acc[i][slot]*rinv[i];
      }
    }
  }
}

// ---------------- p-projection + leaky ----------------
__global__ void k_pproj(const float* __restrict__ Vo, const float* __restrict__ pw,
                        const float* __restrict__ pb, const float* __restrict__ pa,
                        float* __restrict__ pj){
  int i = blockIdx.x*blockDim.x + threadIdx.x;
  if (i >= 2*48*250*65) return;
  int f = i % 65;
  int t = (i/65) % 250;
  int o = (i/(65*250)) % 48;
  int b = i/(65*250*48);
  const float* vp = Vo + (size_t)b*48*250*65 + (size_t)t*65 + f;
  const float* wr = pw + o*48;
  float acc = pb[o];
  for (int c=0;c<48;c++) acc += vp[(size_t)c*250*65]*wr[c];
  if (acc < 0.f) acc *= pa[0];
  pj[i] = acc;
}

// ---------------- ln_clamp over (c,f) per (b,t) + residual ----------------
__global__ void k_pln(const float* __restrict__ pj, const float* __restrict__ pg,
                      const float* __restrict__ pbt, const float* __restrict__ inter,
                      float* __restrict__ outb){
  __shared__ float r1[256];
  __shared__ float r2[256];
  int bx = blockIdx.x;
  int t = bx % 250, b = bx/250;
  const float* base = pj + (size_t)b*48*250*65 + (size_t)t*65;
  float s=0.f, ss=0.f;
  for (int k=threadIdx.x; k<3120; k+=256){
    int c = k/65, f = k%65;
    float v = base[(size_t)c*250*65 + f];
    s+=v; ss+=v*v;
  }
  r1[threadIdx.x]=s; r2[threadIdx.x]=ss; __syncthreads();
  for (int st=128; st>0; st>>=1){
    if (threadIdx.x<st){ r1[threadIdx.x]+=r1[threadIdx.x+st]; r2[threadIdx.x]+=r2[threadIdx.x+st]; }
    __syncthreads();
  }
  float mu = r1[0]*(1.0f/3120.0f), var = r2[0]*(1.0f/3120.0f) - mu*mu;
  float rs = rsqrtf(fmaxf(var, EPSV));
  for (int k=threadIdx.x; k<3120; k+=256){
    int c = k/65, f = k%65;
    size_t idx = (((size_t)b*48+c)*250 + t)*65 + f;
    float v = pj[idx];
    outb[idx] = (v-mu)*rs*pg[c*65+f] + pbt[c*65+f] + inter[idx];
  }
}

// ---------------- fin 1x1 (48->384), 4 outputs/thread ----------------
__global__ void k_fin2(const float* __restrict__ outb, const float* __restrict__ w,
                       const float* __restrict__ bias, float* __restrict__ pi){
  int i = blockIdx.x*blockDim.x + threadIdx.x;
  if (i >= 2*96*250*65) return;
  int f = i % 65;
  int t = (i/65) % 250;
  int og = (i/(65*250)) % 96;
  int b = i/(65*250*96);
  const float* xp = outb + (size_t)b*48*250*65 + (size_t)t*65 + f;
  const float* w0 = w + og*4*48;
  float a0=bias[og*4], a1=bias[og*4+1], a2=bias[og*4+2], a3=bias[og*4+3];
  for (int c=0;c<48;c++){
    float xv = xp[(size_t)c*250*65];
    a0 += xv*w0[c]; a1 += xv*w0[48+c]; a2 += xv*w0[96+c]; a3 += xv*w0[144+c];
  }
  size_t o0 = (((size_t)b*384 + og*4)*250 + t)*65 + f;
  pi[o0] = a0; pi[o0+16250] = a1; pi[o0+2*16250] = a2; pi[o0+3*16250] = a3;
}

// ---------------- depthwise 3x3 both halves + gelu-gate ----------------
__global__ void k_dwg(const float* __restrict__ pi, const float* __restrict__ dw,
                      const float* __restrict__ db, float* __restrict__ gbuf){
  int i = blockIdx.x*blockDim.x + threadIdx.x;
  if (i >= 2*192*250*65) return;
  int f = i % 65;
  int t = (i/65) % 250;
  int j = (i/(65*250)) % 192;
  int b = i/(65*250*192);
  float x12[2];
  for (int half=0; half<2; half++){
    int ch = j + half*192;
    const float* base = pi + ((size_t)b*384 + ch)*250*65;
    const float* wr = dw + ch*9;
    float acc = db[ch];
    for (int dt=-1; dt<=1; dt++){
      int tt = t+dt;
      if (tt<0||tt>=250) continue;
      for (int df=-1; df<=1; df++){
        int ff = f+df;
        if (ff<0||ff>=65) continue;
        acc += base[(size_t)tt*65+ff]*wr[(dt+1)*3 + (df+1)];
      }
    }
    x12[half]=acc;
  }
  float x1 = x12[0];
  float g = 0.5f*x1*(1.0f+erff(x1*0.70710678118654752f));
  gbuf[i] = g * x12[1];
}

// ---------------- final 1x1 (192->48), 4 outputs/thread, + residual -> d_out ----------------
__global__ void k_final2(const float* __restrict__ gbuf, const float* __restrict__ w,
                         const float* __restrict__ bias, const float* __restrict__ outb,
                         float* __restrict__ dout){
  int i = blockIdx.x*blockDim.x + threadIdx.x;
  if (i >= 2*12*250*65) return;
  int f = i % 65;
  int t = (i/65) % 250;
  int og = (i/(65*250)) % 12;
  int b = i/(65*250*12);
  const float* gp = gbuf + (size_t)b*192*250*65 + (size_t)t*65 + f;
  const float* w0 = w + og*4*192;
  float a0=bias[og*4], a1=bias[og*4+1], a2=bias[og*4+2], a3=bias[og*4+3];
  for (int j=0;j<192;j++){
    float gv = gp[(size_t)j*250*65];
    a0 += gv*w0[j]; a1 += gv*w0[192+j]; a2 += gv*w0[384+j]; a3 += gv*w0[576+j];
  }
  size_t o0 = (((size_t)b*48 + og*4)*250 + t)*65 + f;
  dout[o0]         = a0 + outb[o0];
  dout[o0+16250]   = a1 + outb[o0+16250];
  dout[o0+2*16250] = a2 + outb[o0+2*16250];
  dout[o0+3*16250] = a3 + outb[o0+3*16250];
}

extern "C" void kernel_launch(void* const* d_in, const int* in_sizes, int n_in,
                              void* d_out, int out_size, void* d_ws, size_t ws_size,
                              hipStream_t stream) {
  (void)in_sizes; (void)n_in; (void)out_size; (void)ws_size;
  auto in = [&](int i){ return (const float*)d_in[i]; };
  const float* x        = in(0);
  const float* af_in_w  = in(1);  const float* af_in_b  = in(2);
  const float* af_out_w = in(3);  const float* af_out_b = in(4);
  const float* at_in_w  = in(5);  const float* at_in_b  = in(6);
  const float* at_out_w = in(7);  const float* at_out_b = in(8);
  const float* naf_g = in(9),  *naf_b = in(10), *nat_g = in(11), *nat_b = in(12);
  const float* intra_ng = in(13), *intra_nb = in(14), *inter_ng = in(15), *inter_nb = in(16);
  const float* intra_wif = in(17), *intra_whf = in(18), *intra_bif = in(19), *intra_bhf = in(20);
  const float* intra_wib = in(21), *intra_whb = in(22), *intra_bib = in(23), *intra_bhb = in(24);
  const float* inter_wif = in(25), *inter_whf = in(26), *inter_bif = in(27), *inter_bhf = in(28);
  const float* inter_wib = in(29), *inter_whb = in(30), *inter_bib = in(31), *inter_bhb = in(32);
  const float* il_w = in(33), *il_b = in(34), *itl_w = in(35), *itl_b = in(36);
  const float* qw = in(37), *qb = in(38), *qa = in(39), *qg = in(40), *qbt = in(41);
  const float* kw = in(42), *kb = in(43), *ka = in(44), *kg = in(45), *kbt = in(46);
  const float* vw = in(47), *vb = in(48), *va = in(49), *vg = in(50), *vbt = in(51);
  const float* pw = in(52), *pb = in(53), *pa = in(54), *pg = in(55), *pbt = in(56);
  const float* fin_w = in(57), *fin_b = in(58), *fdw_w = in(59), *fdw_b = in(60);
  const float* fout_w = in(61), *fout_b = in(62);

  float* ws = (float*)d_ws;
  float* buf_intra = ws + 0;                        // 1,560,000
  float* buf_bt    = ws + 1560000;                  // 1,560,000
  float* buf_out   = ws + 3120000;                  // 1,560,000
  unsigned int* wpk = (unsigned int*)(ws + 4680000);// 8*73728
  unsigned int* wtp = (unsigned int*)(ws + 5269824);// 2*36864
  float* scr       = ws + 5343552;                  // arena
  // staging
  float* s_seq2 = scr;                              // 1,560,000
  float* s_seq  = scr + 1560000;                    // 1,560,000
  float* s_qkv  = scr + 3120000;                    // 4,680,000
  float* s_att  = scr + 7800000;                    // 1,560,000
  // lstm buffers
  _Float16* s_pre = (_Float16*)(scr + 1560000);     // up to 49,320,960 halfs
  unsigned int* s_rT2 = (unsigned int*)(scr + 26220480); // up to 6,165,120 uints
  // phase3 aliases
  float* s_Qh = scr;                                // 1,040,000
  float* s_KT = scr + 1040000;                      // 1,040,000
  float* s_Vh = scr + 2080000;                      // 1,560,000
  float* s_Vo = scr + 3640000;                      // 1,560,000
  float* s_pj = scr + 5200000;                      // 1,560,000
  // phase4 aliases
  float* s_pi = scr;
  float* s_g  = scr + 12480000;

  const int thr = 256;
  auto cdiv = [](int a, int b){ return (a+b-1)/b; };

  // ---------------- weight prep (single kernel) ----------------
  k_prep<<<cdiv(663552,thr),thr,0,stream>>>(
      intra_wif, intra_whf, intra_wib, intra_whb,
      inter_wif, inter_whf, inter_wib, inter_whb,
      il_w, itl_w, wpk, wtp);

  // ---------------- Phase 1: intra (along Q): N=500, L2=62, SL=65 ----------------
  k_ln_chan<<<cdiv(2*250*65,thr), thr, 0, stream>>>(x, s_seq, intra_ng, intra_nb, 0);
  k_qkv<<<cdiv(500*65*144,thr), thr, 0, stream>>>(s_seq, af_in_w, af_in_b, s_qkv, 500*65);
  k_mha<<<dim3(500,4), 256, 0, stream>>>(s_qkv, s_att, 500, 65);
  k_projres<<<cdiv(500*65*48,thr), thr, 0, stream>>>(s_att, s_seq, af_out_w, af_out_b, s_seq2, 500*65);
  k_rowln<<<cdiv(32500,thr), thr, 0, stream>>>(s_seq2, naf_g, naf_b, 32500);
  {
    const size_t dstr = (size_t)500*62*768;
    k_pregates<<<dim3(4,500), 256, 0, stream>>>(s_seq2, wpk+0*73728, intra_bif, intra_bhf, s_pre,        62, 65);
    k_pregates<<<dim3(4,500), 256, 0, stream>>>(s_seq2, wpk+2*73728, intra_bib, intra_bhb, s_pre + dstr, 62, 65);
  }
  k_lstm5<2><<<dim3(250,2), 1024, 0, stream>>>(s_pre, s_rT2, wpk+1*73728, wpk+3*73728, 500, 62);
  k_convt4<<<dim3(2,500), 256, 0, stream>>>(s_rT2, wtp+0*36864, il_b, x, buf_intra, 62, 65, 0);

  // ---------------- Phase 2: inter (along T): N=130, L2=247, SL=250 ----------------
  k_ln_chan<<<cdiv(2*250*65,thr),thr,0,stream>>>(buf_intra, s_seq, inter_ng, inter_nb, 1);
  k_qkv<<<cdiv(130*250*144,thr),thr,0,stream>>>(s_seq, at_in_w, at_in_b, s_qkv, 130*250);
  k_mha<<<dim3(130,4), 256, 0, stream>>>(s_qkv, s_att, 130, 250);
  k_projres<<<cdiv(130*250*48,thr),thr,0,stream>>>(s_att, s_seq, at_out_w, at_out_b, s_seq2, 130*250);
  k_rowln<<<cdiv(32500,thr),thr,0,stream>>>(s_seq2, nat_g, nat_b, 32500);
  {
    const size_t dstr = (size_t)130*247*768;
    k_pregates<<<dim3(16,130), 256, 0, stream>>>(s_seq2, wpk+4*73728, inter_bif, inter_bhf, s_pre,        247, 250);
    k_pregates<<<dim3(16,130), 256, 0, stream>>>(s_seq2, wpk+6*73728, inter_bib, inter_bhb, s_pre + dstr, 247, 250);
  }
  k_lstm5<1><<<dim3(130,2), 1024, 0, stream>>>(s_pre, s_rT2, wpk+5*73728, wpk+7*73728, 130, 247);
  k_convt4<<<dim3(4,130), 256, 0, stream>>>(s_rT2, wtp+1*36864, itl_b, buf_intra, buf_bt, 247, 250, 1);

  // ---------------- Phase 3: flattened-head attention ----------------
  k_hproj<<<2000,256,0,stream>>>(buf_bt, qw, qb, qa, qg, qbt, s_Qh, 8, 0);
  k_hproj<<<2000,256,0,stream>>>(buf_bt, kw, kb, ka, kg, kbt, s_KT, 8, 1);
  k_hproj<<<2000,256,0,stream>>>(buf_bt, vw, vb, va, vg, vbt, s_Vh, 12, 0);
  k_headattn2<<<dim3(25,8), 256, 0, stream>>>(s_Qh, s_KT, s_Vh, s_Vo);
  k_pproj<<<cdiv(2*48*250*65,thr),thr,0,stream>>>(s_Vo, pw, pb, pa, s_pj);
  k_pln<<<500,256,0,stream>>>(s_pj, pg, pbt, buf_bt, buf_out);

  // ---------------- Phase 4: FFN ----------------
  k_fin2<<<cdiv(2*96*250*65,thr),thr,0,stream>>>(buf_out, fin_w, fin_b, s_pi);
  k_dwg<<<cdiv(2*192*250*65,thr),thr,0,stream>>>(s_pi, fdw_w, fdw_b, s_g);
  k_final2<<<cdiv(2*12*250*65,thr),thr,0,stream>>>(s_g, fout_w, fout_b, buf_out, (float*)d_out);
}